// Round 9
// baseline (359.363 us; speedup 1.0000x reference)
//
#include <hip/hip_runtime.h>
#include <hip/hip_bf16.h>
#include <math.h>

typedef __attribute__((ext_vector_type(4))) float  float4v;
typedef __attribute__((ext_vector_type(2))) float  float2v;
typedef __attribute__((ext_vector_type(8))) short  short8;

#define B_ 8
#define L_ 384
#define H_ 128

__device__ __forceinline__ float bflo(unsigned int u){ unsigned int t = u << 16; float f; __builtin_memcpy(&f,&t,4); return f; }
__device__ __forceinline__ unsigned short f2bf(float f){
  unsigned int t; __builtin_memcpy(&t,&f,4);
  return (unsigned short)((t + 0x7fffu + ((t>>16)&1u)) >> 16);
}
__device__ __forceinline__ float fsig(float x){ return __fdividef(1.f, 1.f + __expf(-x)); }

// lgkm-only barrier: LDS ordering without draining in-flight global loads/stores
__device__ __forceinline__ void barrier_lds(){
  asm volatile("s_waitcnt lgkmcnt(0)\n\ts_barrier" ::: "memory");
}

// ---------------- MFMA row-GEMM body (used by proj kernel) ----------------
template<int K>
__device__ __forceinline__ void mfma_rowgemm_body(
    unsigned short* in_s,
    const float* __restrict__ inA,
    const float* __restrict__ W, const float* __restrict__ bias,
    const float* __restrict__ bias2, float* __restrict__ out,
    int Ntotal, int row0, int ob)
{
  constexpr int KP = K + 2;
  const int tid  = threadIdx.x;
  const int w    = tid >> 6;
  const int l    = tid & 63;
  const int c    = l & 15;
  const int quad = l >> 4;

  #pragma unroll
  for (int it = 0; it < K/32; ++it) {
    int idx = it*256 + tid;
    int r = idx / (K/4);
    int k = (idx % (K/4)) * 4;
    float4v f = *(const float4v*)(inA + (size_t)(row0+r)*K + k);
    unsigned int p0 = (unsigned int)f2bf(f.x) | ((unsigned int)f2bf(f.y) << 16);
    unsigned int p1 = (unsigned int)f2bf(f.z) | ((unsigned int)f2bf(f.w) << 16);
    *(unsigned int*)&in_s[r*KP + k]     = p0;
    *(unsigned int*)&in_s[r*KP + k + 2] = p1;
  }

  const int n = ob + w*16 + c;
  short8 bfr[K/32];
  #pragma unroll
  for (int kt = 0; kt < K/32; ++kt) {
    const float* src = W + (size_t)n*K + kt*32 + quad*8;
    float4v f0 = *(const float4v*)(src);
    float4v f1 = *(const float4v*)(src + 4);
    short8 v;
    v[0]=(short)f2bf(f0[0]); v[1]=(short)f2bf(f0[1]); v[2]=(short)f2bf(f0[2]); v[3]=(short)f2bf(f0[3]);
    v[4]=(short)f2bf(f1[0]); v[5]=(short)f2bf(f1[1]); v[6]=(short)f2bf(f1[2]); v[7]=(short)f2bf(f1[3]);
    bfr[kt] = v;
  }
  __syncthreads();

  const float4v z4 = {0.f,0.f,0.f,0.f};
  float4v acc0 = z4, acc1 = z4;
  #pragma unroll
  for (int kt = 0; kt < K/32; ++kt) {
    short8 a0 = *(const short8*)&in_s[(c     )*KP + kt*32 + quad*8];
    short8 a1 = *(const short8*)&in_s[(16 + c)*KP + kt*32 + quad*8];
    acc0 = __builtin_amdgcn_mfma_f32_16x16x32_bf16(a0, bfr[kt], acc0, 0,0,0);
    acc1 = __builtin_amdgcn_mfma_f32_16x16x32_bf16(a1, bfr[kt], acc1, 0,0,0);
  }

  float bv = bias[n] + (bias2 ? bias2[n] : 0.f);
  #pragma unroll
  for (int mt = 0; mt < 2; ++mt) {
    float4v A = mt ? acc1 : acc0;
    #pragma unroll
    for (int r = 0; r < 4; ++r) {
      int m = mt*16 + quad*4 + r;
      out[(size_t)(row0+m)*Ntotal + n] = A[r] + bv;
    }
  }
}

__global__ __launch_bounds__(256) void proj_mfma_kernel(
    const float* __restrict__ x, const float* __restrict__ y,
    const float* __restrict__ Wup_w, const float* __restrict__ Wup_b,
    const float* __restrict__ Wq_w, const float* __restrict__ Wq_b,
    const float* __restrict__ Wvp_b,
    float* __restrict__ xp, float* __restrict__ yp)
{
  __shared__ __align__(16) unsigned short in_s[32*130];
  int bx = blockIdx.x;
  if (bx < 192)
    mfma_rowgemm_body<128>(in_s, x, Wup_w, Wup_b, nullptr,
                           xp, 128, (bx>>1)*32, (bx&1)*64);
  else {
    bx -= 192;
    mfma_rowgemm_body<128>(in_s, y, Wq_w, Wq_b, Wvp_b,
                           yp, 128, (bx>>1)*32, (bx&1)*64);
  }
}

// Fused additive attention (unchanged from round 8): j-split partials
__global__ __launch_bounds__(256) void attn_kernel(
    const float* __restrict__ xp, const float* __restrict__ yp,
    const float* __restrict__ y, const unsigned char* __restrict__ xmask,
    const unsigned char* __restrict__ ymask, const float* __restrict__ Vw,
    const float* __restrict__ Vb,
    float* __restrict__ ctp0, float* __restrict__ ctp1,
    float* __restrict__ ml)
{
  __shared__ __align__(16) float xp_s[8][128];
  __shared__ __align__(16) float v2_s[128];
  __shared__ __align__(16) float yp_s[32][132];
  __shared__ __align__(16) float yc_s[32][132];
  __shared__ float xm_s[8];
  __shared__ float ym_s[32];
  __shared__ float sv_s;
  const int tid = threadIdx.x;
  const int b   = blockIdx.y;
  const int t0  = blockIdx.x * 8;
  const int jh  = blockIdx.z;      // 0: chunks 0..5, 1: chunks 6..11
  const float C2 = 2.8853900817779268f;   // 2*log2(e)
  {
    int r = tid >> 5, k4 = (tid & 31) * 4;
    float4v f = *(const float4v*)(xp + ((size_t)(b*L_ + t0 + r))*H_ + k4);
    float4v g; g[0]=f[0]*C2; g[1]=f[1]*C2; g[2]=f[2]*C2; g[3]=f[3]*C2;
    *(float4v*)&xp_s[r][k4] = g;
    if (tid < 32) {
      float4v v = *(const float4v*)(Vw + tid*4);
      float4v v2; v2[0]=2.f*v[0]; v2[1]=2.f*v[1]; v2[2]=2.f*v[2]; v2[3]=2.f*v[3];
      *(float4v*)&v2_s[tid*4] = v2;
    }
    if (tid < 8) xm_s[tid] = xmask[b*L_ + t0 + tid] ? 0.f : 1.f;
  }
  __syncthreads();
  if (tid < 32) {
    float4v v = *(const float4v*)&v2_s[tid*4];
    float sm = (v[0]+v[1]) + (v[2]+v[3]);
    #pragma unroll
    for (int off = 16; off >= 1; off >>= 1) sm += __shfl_xor(sm, off);
    if (tid == 0) sv_s = 0.5f*sm + Vb[0];
  }

  float4v rp[4], ry[4];
  unsigned char ymb = 0;
  {
    #pragma unroll
    for (int it = 0; it < 4; ++it) {
      int idx = it*256 + tid; int r = idx >> 5; int k4 = (idx & 31) * 4;
      size_t base = ((size_t)(b*L_ + jh*192 + r))*H_ + k4;
      rp[it] = *(const float4v*)(yp + base);
      ry[it] = *(const float4v*)(y + base);
    }
    if (tid < 32) ymb = ymask[b*L_ + jh*192 + tid];
  }

  const int t = tid >> 5, u = tid & 31;
  float mrun = -__builtin_inff(), lrun = 0.f;
  float a0=0.f, a1=0.f, a2=0.f, a3=0.f;
  float svc = 0.f, xmv = 0.f;

  for (int c = 0; c < 6; ++c) {
    __syncthreads();
    #pragma unroll
    for (int it = 0; it < 4; ++it) {
      int idx = it*256 + tid; int r = idx >> 5; int k4 = (idx & 31) * 4;
      float4v sp; sp[0]=rp[it][0]*C2; sp[1]=rp[it][1]*C2; sp[2]=rp[it][2]*C2; sp[3]=rp[it][3]*C2;
      *(float4v*)&yp_s[r][k4] = sp;
      *(float4v*)&yc_s[r][k4] = ry[it];
    }
    if (tid < 32) ym_s[tid] = ymb ? 0.f : 1.f;
    __syncthreads();
    if (c == 0) { svc = sv_s; xmv = xm_s[t]; }
    if (c < 5) {
      #pragma unroll
      for (int it = 0; it < 4; ++it) {
        int idx = it*256 + tid; int r = idx >> 5; int k4 = (idx & 31) * 4;
        size_t base = ((size_t)(b*L_ + jh*192 + (c+1)*32 + r))*H_ + k4;
        rp[it] = *(const float4v*)(yp + base);
        ry[it] = *(const float4v*)(y + base);
      }
      if (tid < 32) ymb = ymask[b*L_ + jh*192 + (c+1)*32 + tid];
    }

    float sA = 0.f, sB = 0.f;
    {
      const float* yr = yp_s[u];
      const float* xr = xp_s[t];
      #pragma unroll 4
      for (int k = 0; k < 128; k += 4) {
        float4v yv = *(const float4v*)&yr[k];
        float4v xv = *(const float4v*)&xr[k];
        float4v vv = *(const float4v*)&v2_s[k];
        float e0 = __builtin_amdgcn_exp2f(xv[0] + yv[0]);
        sA -= vv[0] * __builtin_amdgcn_rcpf(e0 + 1.f);
        float e1 = __builtin_amdgcn_exp2f(xv[1] + yv[1]);
        sB -= vv[1] * __builtin_amdgcn_rcpf(e1 + 1.f);
        float e2 = __builtin_amdgcn_exp2f(xv[2] + yv[2]);
        sA -= vv[2] * __builtin_amdgcn_rcpf(e2 + 1.f);
        float e3 = __builtin_amdgcn_exp2f(xv[3] + yv[3]);
        sB -= vv[3] * __builtin_amdgcn_rcpf(e3 + 1.f);
      }
    }
    float ymv = ym_s[u];
    float s = (svc + sA + sB) * xmv * ymv;
    if (ymv == 0.f) s = -__builtin_inff();
    float mc = s;
    #pragma unroll
    for (int off = 16; off >= 1; off >>= 1) mc = fmaxf(mc, __shfl_xor(mc, off));
    float mnew = fmaxf(mrun, mc);
    float p  = __expf(s - mnew);
    float sc = __expf(mrun - mnew);
    float ps = p;
    #pragma unroll
    for (int off = 16; off >= 1; off >>= 1) ps += __shfl_xor(ps, off);
    lrun = lrun * sc + ps;
    mrun = mnew;
    a0 *= sc; a1 *= sc; a2 *= sc; a3 *= sc;
    #pragma unroll 8
    for (int j = 0; j < 32; ++j) {
      float pv = __shfl(p, j, 32);
      float4v yv = *(const float4v*)&yc_s[j][u*4];
      a0 += pv*yv[0]; a1 += pv*yv[1]; a2 += pv*yv[2]; a3 += pv*yv[3];
    }
  }
  const int row = b*L_ + t0 + t;
  float* ctp = jh ? ctp1 : ctp0;
  float4v ov; ov[0]=a0; ov[1]=a1; ov[2]=a2; ov[3]=a3;     // unnormalized
  *(float4v*)(ctp + (size_t)row*H_ + u*4) = ov;
  if (u == 0) {
    ml[(jh*2+0)*3072 + row] = mrun;
    ml[(jh*2+1)*3072 + row] = lrun;
  }
}

// ---------------- Fused gating pipeline ----------------
// One kernel: (a) merge attn partials inline while staging merge=[x|ct] bf16,
// (b) lstm_in = sigmoid(merge@Wg^T + b)*merge  -> LDS only,
// (c) gates_x = lstm_in@W_ih^T + (b_ih+b_hh)   -> gate-interleaved gx.
// 48 blocks x 512 thr (8 waves), 64 rows/block. Weights read as B-frags from
// global (L2-resident; 48 blocks reuse).
__global__ __launch_bounds__(512) void fused_gate_kernel(
    const float* __restrict__ x,
    const float* __restrict__ ctp0, const float* __restrict__ ctp1,
    const float* __restrict__ ml,
    const float* __restrict__ Wg_w, const float* __restrict__ Wg_b,
    const float* __restrict__ W_ih, const float* __restrict__ b_ih,
    const float* __restrict__ b_hh, float* __restrict__ gx)
{
  constexpr int KP = 258;   // in_s row stride (bf16 elems)
  constexpr int LP = 264;   // li_s row stride (16B-aligned rows, 2-way-free banks)
  __shared__ __align__(16) unsigned short in_s[64*KP];
  __shared__ __align__(16) unsigned short li_s[64*LP];
  const int tid  = threadIdx.x;
  const int w    = tid >> 6;
  const int l    = tid & 63;
  const int c    = l & 15;
  const int quad = l >> 4;
  const int row0 = blockIdx.x * 64;
  const float4v z4 = {0.f,0.f,0.f,0.f};

  // (a) stage merge rows: k<128 from x; k>=128 merged ct from partials
  #pragma unroll
  for (int it = 0; it < 8; ++it) {
    int idx = it*512 + tid;
    int r = idx >> 6;
    int k = (idx & 63) * 4;
    int row = row0 + r;
    float4v f;
    if (k < 128) {
      f = *(const float4v*)(x + (size_t)row*128 + k);
    } else {
      float m0 = ml[row],        l0 = ml[3072 + row];
      float m1 = ml[2*3072+row], l1 = ml[3*3072 + row];
      float mm = fmaxf(m0, m1);
      float e0 = __expf(m0 - mm), e1 = __expf(m1 - mm);
      float inv = __fdividef(1.f, l0*e0 + l1*e1);
      float4v v0 = *(const float4v*)(ctp0 + (size_t)row*128 + (k-128));
      float4v v1 = *(const float4v*)(ctp1 + (size_t)row*128 + (k-128));
      f[0] = (v0[0]*e0 + v1[0]*e1)*inv;
      f[1] = (v0[1]*e0 + v1[1]*e1)*inv;
      f[2] = (v0[2]*e0 + v1[2]*e1)*inv;
      f[3] = (v0[3]*e0 + v1[3]*e1)*inv;
    }
    unsigned int p0 = (unsigned int)f2bf(f[0]) | ((unsigned int)f2bf(f[1]) << 16);
    unsigned int p1 = (unsigned int)f2bf(f[2]) | ((unsigned int)f2bf(f[3]) << 16);
    *(unsigned int*)&in_s[r*KP + k]     = p0;
    *(unsigned int*)&in_s[r*KP + k + 2] = p1;
  }
  __syncthreads();

  // (b) G1: wave w handles n-tiles {w, w+8} of N=256
  {
    short8 bfr[2][8];
    #pragma unroll
    for (int i = 0; i < 2; ++i) {
      int n = (w + i*8)*16 + c;
      #pragma unroll
      for (int kt = 0; kt < 8; ++kt) {
        const float* src = Wg_w + (size_t)n*256 + kt*32 + quad*8;
        float4v f0 = *(const float4v*)(src);
        float4v f1 = *(const float4v*)(src + 4);
        short8 v;
        v[0]=(short)f2bf(f0[0]); v[1]=(short)f2bf(f0[1]); v[2]=(short)f2bf(f0[2]); v[3]=(short)f2bf(f0[3]);
        v[4]=(short)f2bf(f1[0]); v[5]=(short)f2bf(f1[1]); v[6]=(short)f2bf(f1[2]); v[7]=(short)f2bf(f1[3]);
        bfr[i][kt] = v;
      }
    }
    float4v acc[2][4];
    #pragma unroll
    for (int i=0;i<2;++i)
      #pragma unroll
      for (int mt=0;mt<4;++mt) acc[i][mt] = z4;
    #pragma unroll
    for (int kt = 0; kt < 8; ++kt) {
      short8 a[4];
      #pragma unroll
      for (int mt = 0; mt < 4; ++mt)
        a[mt] = *(const short8*)&in_s[(mt*16 + c)*KP + kt*32 + quad*8];
      #pragma unroll
      for (int i = 0; i < 2; ++i)
        #pragma unroll
        for (int mt = 0; mt < 4; ++mt)
          acc[i][mt] = __builtin_amdgcn_mfma_f32_16x16x32_bf16(a[mt], bfr[i][kt], acc[i][mt], 0,0,0);
    }
    #pragma unroll
    for (int i = 0; i < 2; ++i) {
      int n = (w + i*8)*16 + c;
      float bv = Wg_b[n];
      #pragma unroll
      for (int mt = 0; mt < 4; ++mt)
        #pragma unroll
        for (int r = 0; r < 4; ++r) {
          int m = mt*16 + quad*4 + r;
          float val = acc[i][mt][r] + bv;
          float mg = bflo((unsigned int)in_s[m*KP + n]);
          li_s[m*LP + n] = f2bf(fsig(val) * mg);
        }
    }
  }
  __syncthreads();

  // (c) G2: N=512 in 2 passes of 2 tiles/wave; A from li_s
  #pragma unroll
  for (int p = 0; p < 2; ++p) {
    short8 bfr[2][8];
    #pragma unroll
    for (int i = 0; i < 2; ++i) {
      int n = (w + i*8 + p*16)*16 + c;
      #pragma unroll
      for (int kt = 0; kt < 8; ++kt) {
        const float* src = W_ih + (size_t)n*256 + kt*32 + quad*8;
        float4v f0 = *(const float4v*)(src);
        float4v f1 = *(const float4v*)(src + 4);
        short8 v;
        v[0]=(short)f2bf(f0[0]); v[1]=(short)f2bf(f0[1]); v[2]=(short)f2bf(f0[2]); v[3]=(short)f2bf(f0[3]);
        v[4]=(short)f2bf(f1[0]); v[5]=(short)f2bf(f1[1]); v[6]=(short)f2bf(f1[2]); v[7]=(short)f2bf(f1[3]);
        bfr[i][kt] = v;
      }
    }
    float4v acc[2][4];
    #pragma unroll
    for (int i=0;i<2;++i)
      #pragma unroll
      for (int mt=0;mt<4;++mt) acc[i][mt] = z4;
    #pragma unroll
    for (int kt = 0; kt < 8; ++kt) {
      short8 a[4];
      #pragma unroll
      for (int mt = 0; mt < 4; ++mt)
        a[mt] = *(const short8*)&li_s[(mt*16 + c)*LP + kt*32 + quad*8];
      #pragma unroll
      for (int i = 0; i < 2; ++i)
        #pragma unroll
        for (int mt = 0; mt < 4; ++mt)
          acc[i][mt] = __builtin_amdgcn_mfma_f32_16x16x32_bf16(a[mt], bfr[i][kt], acc[i][mt], 0,0,0);
    }
    #pragma unroll
    for (int i = 0; i < 2; ++i) {
      int n = (w + i*8 + p*16)*16 + c;
      float bv = b_ih[n] + b_hh[n];
      #pragma unroll
      for (int mt = 0; mt < 4; ++mt)
        #pragma unroll
        for (int r = 0; r < 4; ++r) {
          int m = mt*16 + quad*4 + r;
          gx[(size_t)(row0+m)*512 + (n & 127)*4 + (n >> 7)] = acc[i][mt][r] + bv;
        }
    }
  }
}

// LSTM scan — round-5 body (measured 180 µs; best). Untouched.
__global__ __launch_bounds__(512) void lstm_kernel(
    const float* __restrict__ gx, const float* __restrict__ Whh,
    float* __restrict__ out)
{
  __shared__ __align__(16) unsigned short h_s[2][128];
  const int tid  = threadIdx.x;
  const int b    = blockIdx.x;
  const int w    = tid >> 6;
  const int l    = tid & 63;
  const int col  = l & 15;
  const int quad = l >> 4;

  short8 bf[4][4];
  #pragma unroll
  for (int nt = 0; nt < 4; ++nt) {
    const int n = nt*128 + w*16 + col;
    #pragma unroll
    for (int kt = 0; kt < 4; ++kt) {
      const int k0 = kt*32 + quad*8;
      const float* src = Whh + (size_t)n*H_ + k0;
      float4v f0 = *(const float4v*)(src);
      float4v f1 = *(const float4v*)(src + 4);
      short8 v;
      v[0]=(short)f2bf(f0[0]); v[1]=(short)f2bf(f0[1]); v[2]=(short)f2bf(f0[2]); v[3]=(short)f2bf(f0[3]);
      v[4]=(short)f2bf(f1[0]); v[5]=(short)f2bf(f1[1]); v[6]=(short)f2bf(f1[2]); v[7]=(short)f2bf(f1[3]);
      bf[nt][kt] = v;
    }
  }

  if (tid < 128) { h_s[0][tid] = 0; h_s[1][tid] = 0; }
  float cst = 0.f;
  const int goff = w*16 + col;
  const float* gbase = gx + (size_t)b*L_*512 + goff*4;
  float* outp = out + (size_t)b*L_*H_ + goff;
  float4v gbuf[4];
  #pragma unroll
  for (int s = 0; s < 4; ++s)
    gbuf[s] = *(const float4v*)(gbase + (size_t)s*512);
  const float4v z4 = {0.f,0.f,0.f,0.f};
  const float NL2E = -1.4426950408889634f;   // -log2(e)
  const float P2L2E = 2.8853900817779268f;   //  2*log2(e)
  __syncthreads();

  for (int t4 = 0; t4 < L_; t4 += 4) {
    #pragma unroll
    for (int s = 0; s < 4; ++s) {
      const int tstep = t4 + s;
      const unsigned short* hb = h_s[s & 1];
      short8 a[4];
      #pragma unroll
      for (int kt=0;kt<4;++kt) a[kt] = *(const short8*)&hb[kt*32 + quad*8];
      float4v c0 = z4, c1 = z4, c2 = z4, c3 = z4;
      #pragma unroll
      for (int kt=0;kt<4;++kt) {
        c0 = __builtin_amdgcn_mfma_f32_16x16x32_bf16(a[kt], bf[0][kt], c0, 0,0,0);
        c1 = __builtin_amdgcn_mfma_f32_16x16x32_bf16(a[kt], bf[1][kt], c1, 0,0,0);
        c2 = __builtin_amdgcn_mfma_f32_16x16x32_bf16(a[kt], bf[2][kt], c2, 0,0,0);
        c3 = __builtin_amdgcn_mfma_f32_16x16x32_bf16(a[kt], bf[3][kt], c3, 0,0,0);
      }
      float g0 = c0[0] + gbuf[s][0];
      float g1 = c1[0] + gbuf[s][1];
      float g2 = c2[0] + gbuf[s][2];
      float g3 = c3[0] + gbuf[s][3];
      if (tstep + 4 < L_)
        gbuf[s] = *(const float4v*)(gbase + (size_t)(tstep+4)*512);
      if (quad == 0) {
        float ig = __builtin_amdgcn_rcpf(1.f + __builtin_amdgcn_exp2f(NL2E*g0));
        float fg = __builtin_amdgcn_rcpf(1.f + __builtin_amdgcn_exp2f(NL2E*g1));
        float gg = 1.f - 2.f*__builtin_amdgcn_rcpf(__builtin_amdgcn_exp2f(P2L2E*g2) + 1.f);
        float og = __builtin_amdgcn_rcpf(1.f + __builtin_amdgcn_exp2f(NL2E*g3));
        cst = fg*cst + ig*gg;
        float hn = og * (1.f - 2.f*__builtin_amdgcn_rcpf(__builtin_amdgcn_exp2f(P2L2E*cst) + 1.f));
        outp[(size_t)tstep*H_] = hn;
        h_s[(s+1)&1][goff] = f2bf(hn);
      }
      barrier_lds();
    }
  }
}

extern "C" void kernel_launch(void* const* d_in, const int* in_sizes, int n_in,
                              void* d_out, int out_size, void* d_ws, size_t ws_size,
                              hipStream_t stream)
{
  (void)in_sizes; (void)n_in; (void)out_size; (void)ws_size;
  const float* x     = (const float*)d_in[0];
  const unsigned char* xm = (const unsigned char*)d_in[1];
  const float* y     = (const float*)d_in[2];
  const unsigned char* ym = (const unsigned char*)d_in[3];
  const float* Wq_w  = (const float*)d_in[4];
  const float* Wq_b  = (const float*)d_in[5];
  const float* Wup_w = (const float*)d_in[6];
  const float* Wup_b = (const float*)d_in[7];
  const float* Wvp_b = (const float*)d_in[9];
  const float* V_w   = (const float*)d_in[10];
  const float* V_b   = (const float*)d_in[11];
  const float* Wg_w  = (const float*)d_in[12];
  const float* Wg_b  = (const float*)d_in[13];
  const float* W_ih  = (const float*)d_in[14];
  const float* W_hh  = (const float*)d_in[15];
  const float* b_ih  = (const float*)d_in[16];
  const float* b_hh  = (const float*)d_in[17];
  float* out = (float*)d_out;

  float* wsf    = (float*)d_ws;
  float* xp_ws  = wsf;                   // [3072][128]
  float* yp_ws  = xp_ws + 393216;        // [3072][128]
  float* ctp0_ws= yp_ws + 393216;        // [3072][128] half-0 partial
  float* ctp1_ws= ctp0_ws + 393216;      // [3072][128] half-1 partial
  float* gx_ws  = ctp1_ws + 393216;      // [3072][512] gate-interleaved
  float* ml_ws  = gx_ws + 1572864;       // [4][3072]  (m0,l0,m1,l1)

  proj_mfma_kernel<<<dim3(384),256,0,stream>>>(x, y, Wup_w, Wup_b, Wq_w, Wq_b, Wvp_b, xp_ws, yp_ws);
  attn_kernel<<<dim3(48,8,2),256,0,stream>>>(xp_ws, yp_ws, y, xm, ym, V_w, V_b, ctp0_ws, ctp1_ws, ml_ws);
  fused_gate_kernel<<<dim3(48),512,0,stream>>>(x, ctp0_ws, ctp1_ws, ml_ws,
                                               Wg_w, Wg_b, W_ih, b_ih, b_hh, gx_ws);
  lstm_kernel<<<dim3(8),512,0,stream>>>(gx_ws, W_hh, out);
}

// Round 10
// 338.124 us; speedup vs baseline: 1.0628x; 1.0628x over previous
//
#include <hip/hip_runtime.h>
#include <hip/hip_bf16.h>
#include <math.h>

typedef __attribute__((ext_vector_type(4))) float  float4v;
typedef __attribute__((ext_vector_type(2))) float  float2v;
typedef __attribute__((ext_vector_type(8))) short  short8;

#define B_ 8
#define L_ 384
#define H_ 128

__device__ __forceinline__ float bflo(unsigned int u){ unsigned int t = u << 16; float f; __builtin_memcpy(&f,&t,4); return f; }
__device__ __forceinline__ unsigned short f2bf(float f){
  unsigned int t; __builtin_memcpy(&t,&f,4);
  return (unsigned short)((t + 0x7fffu + ((t>>16)&1u)) >> 16);
}
__device__ __forceinline__ float fsig(float x){ return __fdividef(1.f, 1.f + __expf(-x)); }

// lgkm-only barrier: LDS ordering without draining in-flight global loads/stores
__device__ __forceinline__ void barrier_lds(){
  asm volatile("s_waitcnt lgkmcnt(0)\n\ts_barrier" ::: "memory");
}

// ---------------- MFMA row-GEMM (R8 structure) ----------------
// act==0: linear.  act==2: sigmoid-gate vs staged input.  act==3: linear,
// gate-interleaved scatter.  act==4: out = exp2(C2*val)  (attn exp precompute)
template<int K>
__device__ __forceinline__ void mfma_rowgemm_body(
    unsigned short* in_s,
    const float* __restrict__ inA, const float* __restrict__ inB,
    const float* __restrict__ W, const float* __restrict__ bias,
    const float* __restrict__ bias2, float* __restrict__ out,
    int Ntotal, int act, int row0, int ob)
{
  constexpr int KP = K + 2;
  const int tid  = threadIdx.x;
  const int w    = tid >> 6;
  const int l    = tid & 63;
  const int c    = l & 15;
  const int quad = l >> 4;

  #pragma unroll
  for (int it = 0; it < K/32; ++it) {
    int idx = it*256 + tid;
    int r = idx / (K/4);
    int k = (idx % (K/4)) * 4;
    float4v f;
    if (inB != nullptr && k >= 128)
      f = *(const float4v*)(inB + (size_t)(row0+r)*128 + (k-128));
    else if (inB != nullptr)
      f = *(const float4v*)(inA + (size_t)(row0+r)*128 + k);
    else
      f = *(const float4v*)(inA + (size_t)(row0+r)*K + k);
    unsigned int p0 = (unsigned int)f2bf(f.x) | ((unsigned int)f2bf(f.y) << 16);
    unsigned int p1 = (unsigned int)f2bf(f.z) | ((unsigned int)f2bf(f.w) << 16);
    *(unsigned int*)&in_s[r*KP + k]     = p0;
    *(unsigned int*)&in_s[r*KP + k + 2] = p1;
  }

  const int n = ob + w*16 + c;
  short8 bfr[K/32];
  #pragma unroll
  for (int kt = 0; kt < K/32; ++kt) {
    const float* src = W + (size_t)n*K + kt*32 + quad*8;
    float4v f0 = *(const float4v*)(src);
    float4v f1 = *(const float4v*)(src + 4);
    short8 v;
    v[0]=(short)f2bf(f0[0]); v[1]=(short)f2bf(f0[1]); v[2]=(short)f2bf(f0[2]); v[3]=(short)f2bf(f0[3]);
    v[4]=(short)f2bf(f1[0]); v[5]=(short)f2bf(f1[1]); v[6]=(short)f2bf(f1[2]); v[7]=(short)f2bf(f1[3]);
    bfr[kt] = v;
  }
  __syncthreads();

  const float4v z4 = {0.f,0.f,0.f,0.f};
  float4v acc0 = z4, acc1 = z4;
  #pragma unroll
  for (int kt = 0; kt < K/32; ++kt) {
    short8 a0 = *(const short8*)&in_s[(c     )*KP + kt*32 + quad*8];
    short8 a1 = *(const short8*)&in_s[(16 + c)*KP + kt*32 + quad*8];
    acc0 = __builtin_amdgcn_mfma_f32_16x16x32_bf16(a0, bfr[kt], acc0, 0,0,0);
    acc1 = __builtin_amdgcn_mfma_f32_16x16x32_bf16(a1, bfr[kt], acc1, 0,0,0);
  }

  const float C2 = 2.8853900817779268f;   // 2*log2(e)
  float bv = bias[n] + (bias2 ? bias2[n] : 0.f);
  #pragma unroll
  for (int mt = 0; mt < 2; ++mt) {
    float4v A = mt ? acc1 : acc0;
    #pragma unroll
    for (int r = 0; r < 4; ++r) {
      int m = mt*16 + quad*4 + r;
      float val = A[r] + bv;
      if (act == 2) {
        float mg = bflo((unsigned int)in_s[m*KP + n]);
        val = fsig(val) * mg;
      }
      if (act == 4)
        val = __builtin_amdgcn_exp2f(C2 * val);
      if (act == 3)
        out[(size_t)(row0+m)*Ntotal + (n & 127)*4 + (n >> 7)] = val;
      else
        out[(size_t)(row0+m)*Ntotal + n] = val;
    }
  }
}

template<int K>
__global__ __launch_bounds__(256) void mfma_rowgemm_kernel(
    const float* __restrict__ inA, const float* __restrict__ inB,
    const float* __restrict__ W, const float* __restrict__ bias,
    const float* __restrict__ bias2, float* __restrict__ out,
    int Ntotal, int act)
{
  __shared__ __align__(16) unsigned short in_s[32*(K+2)];
  mfma_rowgemm_body<K>(in_s, inA, inB, W, bias, bias2, out,
                       Ntotal, act, blockIdx.x*32, blockIdx.y*64);
}

// Projections now emit Ex = exp2(C2*x_proj), Ey = exp2(C2*y_proj2) (act==4):
// attn uses only the exp of the projections (exp-homomorphism trick).
__global__ __launch_bounds__(256) void proj_mfma_kernel(
    const float* __restrict__ x, const float* __restrict__ y,
    const float* __restrict__ Wup_w, const float* __restrict__ Wup_b,
    const float* __restrict__ Wq_w, const float* __restrict__ Wq_b,
    const float* __restrict__ Wvp_b,
    float* __restrict__ xp, float* __restrict__ yp)
{
  __shared__ __align__(16) unsigned short in_s[32*130];
  int bx = blockIdx.x;
  if (bx < 192)
    mfma_rowgemm_body<128>(in_s, x, nullptr, Wup_w, Wup_b, nullptr,
                           xp, 128, 4, (bx>>1)*32, (bx&1)*64);
  else {
    bx -= 192;
    mfma_rowgemm_body<128>(in_s, y, nullptr, Wq_w, Wq_b, Wvp_b,
                           yp, 128, 4, (bx>>1)*32, (bx&1)*64);
  }
}

// Fused additive attention, round-10: inputs are PRE-EXPONENTIATED (Ex, Ey).
// tanh term = 1 - 2*rcp(Ex*Ey + 1): 2 VALU + 1 trans per element (halved
// trans vs round 8). j-split partials (blockIdx.z) as in round 8.
__global__ __launch_bounds__(256) void attn_kernel(
    const float* __restrict__ xp, const float* __restrict__ yp,
    const float* __restrict__ y, const unsigned char* __restrict__ xmask,
    const unsigned char* __restrict__ ymask, const float* __restrict__ Vw,
    const float* __restrict__ Vb,
    float* __restrict__ ctp0, float* __restrict__ ctp1,
    float* __restrict__ ml)
{
  __shared__ __align__(16) float xp_s[8][128];
  __shared__ __align__(16) float v2_s[128];
  __shared__ __align__(16) float yp_s[32][132];
  __shared__ __align__(16) float yc_s[32][132];
  __shared__ float xm_s[8];
  __shared__ float ym_s[32];
  __shared__ float sv_s;
  const int tid = threadIdx.x;
  const int b   = blockIdx.y;
  const int t0  = blockIdx.x * 8;
  const int jh  = blockIdx.z;      // 0: chunks 0..5, 1: chunks 6..11
  {
    int r = tid >> 5, k4 = (tid & 31) * 4;
    float4v f = *(const float4v*)(xp + ((size_t)(b*L_ + t0 + r))*H_ + k4);
    *(float4v*)&xp_s[r][k4] = f;          // Ex, no transform
    if (tid < 32) {
      float4v v = *(const float4v*)(Vw + tid*4);
      float4v v2; v2[0]=2.f*v[0]; v2[1]=2.f*v[1]; v2[2]=2.f*v[2]; v2[3]=2.f*v[3];
      *(float4v*)&v2_s[tid*4] = v2;
    }
    if (tid < 8) xm_s[tid] = xmask[b*L_ + t0 + tid] ? 0.f : 1.f;
  }
  __syncthreads();
  if (tid < 32) {
    float4v v = *(const float4v*)&v2_s[tid*4];
    float sm = (v[0]+v[1]) + (v[2]+v[3]);
    #pragma unroll
    for (int off = 16; off >= 1; off >>= 1) sm += __shfl_xor(sm, off);
    if (tid == 0) sv_s = 0.5f*sm + Vb[0];
  }

  float4v rp[4], ry[4];
  unsigned char ymb = 0;
  {
    #pragma unroll
    for (int it = 0; it < 4; ++it) {
      int idx = it*256 + tid; int r = idx >> 5; int k4 = (idx & 31) * 4;
      size_t base = ((size_t)(b*L_ + jh*192 + r))*H_ + k4;
      rp[it] = *(const float4v*)(yp + base);
      ry[it] = *(const float4v*)(y + base);
    }
    if (tid < 32) ymb = ymask[b*L_ + jh*192 + tid];
  }

  const int t = tid >> 5, u = tid & 31;
  float mrun = -__builtin_inff(), lrun = 0.f;
  float a0=0.f, a1=0.f, a2=0.f, a3=0.f;
  float svc = 0.f, xmv = 0.f;

  for (int c = 0; c < 6; ++c) {
    __syncthreads();
    #pragma unroll
    for (int it = 0; it < 4; ++it) {
      int idx = it*256 + tid; int r = idx >> 5; int k4 = (idx & 31) * 4;
      *(float4v*)&yp_s[r][k4] = rp[it];   // Ey, no transform
      *(float4v*)&yc_s[r][k4] = ry[it];
    }
    if (tid < 32) ym_s[tid] = ymb ? 0.f : 1.f;
    __syncthreads();
    if (c == 0) { svc = sv_s; xmv = xm_s[t]; }
    if (c < 5) {
      #pragma unroll
      for (int it = 0; it < 4; ++it) {
        int idx = it*256 + tid; int r = idx >> 5; int k4 = (idx & 31) * 4;
        size_t base = ((size_t)(b*L_ + jh*192 + (c+1)*32 + r))*H_ + k4;
        rp[it] = *(const float4v*)(yp + base);
        ry[it] = *(const float4v*)(y + base);
      }
      if (tid < 32) ymb = ymask[b*L_ + jh*192 + (c+1)*32 + tid];
    }

    float sA = 0.f, sB = 0.f;
    {
      const float* yr = yp_s[u];
      const float* xr = xp_s[t];
      #pragma unroll 4
      for (int k = 0; k < 128; k += 4) {
        float4v yv = *(const float4v*)&yr[k];
        float4v xv = *(const float4v*)&xr[k];
        float4v vv = *(const float4v*)&v2_s[k];
        sA -= vv[0] * __builtin_amdgcn_rcpf(__builtin_fmaf(xv[0], yv[0], 1.f));
        sB -= vv[1] * __builtin_amdgcn_rcpf(__builtin_fmaf(xv[1], yv[1], 1.f));
        sA -= vv[2] * __builtin_amdgcn_rcpf(__builtin_fmaf(xv[2], yv[2], 1.f));
        sB -= vv[3] * __builtin_amdgcn_rcpf(__builtin_fmaf(xv[3], yv[3], 1.f));
      }
    }
    float ymv = ym_s[u];
    float s = (svc + sA + sB) * xmv * ymv;
    if (ymv == 0.f) s = -__builtin_inff();
    float mc = s;
    #pragma unroll
    for (int off = 16; off >= 1; off >>= 1) mc = fmaxf(mc, __shfl_xor(mc, off));
    float mnew = fmaxf(mrun, mc);
    float p  = __expf(s - mnew);
    float sc = __expf(mrun - mnew);
    float ps = p;
    #pragma unroll
    for (int off = 16; off >= 1; off >>= 1) ps += __shfl_xor(ps, off);
    lrun = lrun * sc + ps;
    mrun = mnew;
    a0 *= sc; a1 *= sc; a2 *= sc; a3 *= sc;
    #pragma unroll 8
    for (int j = 0; j < 32; ++j) {
      float pv = __shfl(p, j, 32);
      float4v yv = *(const float4v*)&yc_s[j][u*4];
      a0 += pv*yv[0]; a1 += pv*yv[1]; a2 += pv*yv[2]; a3 += pv*yv[3];
    }
  }
  const int row = b*L_ + t0 + t;
  float* ctp = jh ? ctp1 : ctp0;
  float4v ov; ov[0]=a0; ov[1]=a1; ov[2]=a2; ov[3]=a3;     // unnormalized
  *(float4v*)(ctp + (size_t)row*H_ + u*4) = ov;
  if (u == 0) {
    ml[(jh*2+0)*3072 + row] = mrun;
    ml[(jh*2+1)*3072 + row] = lrun;
  }
}

// Merge the two j-half partials: ct = (ct0*e0 + ct1*e1) / (l0*e0 + l1*e1)
__global__ __launch_bounds__(256) void attn_merge_kernel(
    const float* __restrict__ ctp0, const float* __restrict__ ctp1,
    const float* __restrict__ ml, float* __restrict__ ct)
{
  const int tid = threadIdx.x;
  const int row = blockIdx.x*8 + (tid >> 5);
  const int c4  = (tid & 31) * 4;
  float m0 = ml[row],        l0 = ml[3072 + row];
  float m1 = ml[2*3072+row], l1 = ml[3*3072 + row];
  float m  = fmaxf(m0, m1);
  float e0 = __expf(m0 - m), e1 = __expf(m1 - m);
  float inv = __fdividef(1.f, l0*e0 + l1*e1);
  float4v v0 = *(const float4v*)(ctp0 + (size_t)row*H_ + c4);
  float4v v1 = *(const float4v*)(ctp1 + (size_t)row*H_ + c4);
  float4v r;
  r[0] = (v0[0]*e0 + v1[0]*e1)*inv;
  r[1] = (v0[1]*e0 + v1[1]*e1)*inv;
  r[2] = (v0[2]*e0 + v1[2]*e1)*inv;
  r[3] = (v0[3]*e0 + v1[3]*e1)*inv;
  *(float4v*)(ct + (size_t)row*H_ + c4) = r;
}

// LSTM scan — round-5 body (measured 180 µs; best). Untouched.
__global__ __launch_bounds__(512) void lstm_kernel(
    const float* __restrict__ gx, const float* __restrict__ Whh,
    float* __restrict__ out)
{
  __shared__ __align__(16) unsigned short h_s[2][128];
  const int tid  = threadIdx.x;
  const int b    = blockIdx.x;
  const int w    = tid >> 6;
  const int l    = tid & 63;
  const int col  = l & 15;
  const int quad = l >> 4;

  short8 bf[4][4];
  #pragma unroll
  for (int nt = 0; nt < 4; ++nt) {
    const int n = nt*128 + w*16 + col;
    #pragma unroll
    for (int kt = 0; kt < 4; ++kt) {
      const int k0 = kt*32 + quad*8;
      const float* src = Whh + (size_t)n*H_ + k0;
      float4v f0 = *(const float4v*)(src);
      float4v f1 = *(const float4v*)(src + 4);
      short8 v;
      v[0]=(short)f2bf(f0[0]); v[1]=(short)f2bf(f0[1]); v[2]=(short)f2bf(f0[2]); v[3]=(short)f2bf(f0[3]);
      v[4]=(short)f2bf(f1[0]); v[5]=(short)f2bf(f1[1]); v[6]=(short)f2bf(f1[2]); v[7]=(short)f2bf(f1[3]);
      bf[nt][kt] = v;
    }
  }

  if (tid < 128) { h_s[0][tid] = 0; h_s[1][tid] = 0; }
  float cst = 0.f;
  const int goff = w*16 + col;
  const float* gbase = gx + (size_t)b*L_*512 + goff*4;
  float* outp = out + (size_t)b*L_*H_ + goff;
  float4v gbuf[4];
  #pragma unroll
  for (int s = 0; s < 4; ++s)
    gbuf[s] = *(const float4v*)(gbase + (size_t)s*512);
  const float4v z4 = {0.f,0.f,0.f,0.f};
  const float NL2E = -1.4426950408889634f;   // -log2(e)
  const float P2L2E = 2.8853900817779268f;   //  2*log2(e)
  __syncthreads();

  for (int t4 = 0; t4 < L_; t4 += 4) {
    #pragma unroll
    for (int s = 0; s < 4; ++s) {
      const int tstep = t4 + s;
      const unsigned short* hb = h_s[s & 1];
      short8 a[4];
      #pragma unroll
      for (int kt=0;kt<4;++kt) a[kt] = *(const short8*)&hb[kt*32 + quad*8];
      float4v c0 = z4, c1 = z4, c2 = z4, c3 = z4;
      #pragma unroll
      for (int kt=0;kt<4;++kt) {
        c0 = __builtin_amdgcn_mfma_f32_16x16x32_bf16(a[kt], bf[0][kt], c0, 0,0,0);
        c1 = __builtin_amdgcn_mfma_f32_16x16x32_bf16(a[kt], bf[1][kt], c1, 0,0,0);
        c2 = __builtin_amdgcn_mfma_f32_16x16x32_bf16(a[kt], bf[2][kt], c2, 0,0,0);
        c3 = __builtin_amdgcn_mfma_f32_16x16x32_bf16(a[kt], bf[3][kt], c3, 0,0,0);
      }
      float g0 = c0[0] + gbuf[s][0];
      float g1 = c1[0] + gbuf[s][1];
      float g2 = c2[0] + gbuf[s][2];
      float g3 = c3[0] + gbuf[s][3];
      if (tstep + 4 < L_)
        gbuf[s] = *(const float4v*)(gbase + (size_t)(tstep+4)*512);
      if (quad == 0) {
        float ig = __builtin_amdgcn_rcpf(1.f + __builtin_amdgcn_exp2f(NL2E*g0));
        float fg = __builtin_amdgcn_rcpf(1.f + __builtin_amdgcn_exp2f(NL2E*g1));
        float gg = 1.f - 2.f*__builtin_amdgcn_rcpf(__builtin_amdgcn_exp2f(P2L2E*g2) + 1.f);
        float og = __builtin_amdgcn_rcpf(1.f + __builtin_amdgcn_exp2f(NL2E*g3));
        cst = fg*cst + ig*gg;
        float hn = og * (1.f - 2.f*__builtin_amdgcn_rcpf(__builtin_amdgcn_exp2f(P2L2E*cst) + 1.f));
        outp[(size_t)tstep*H_] = hn;
        h_s[(s+1)&1][goff] = f2bf(hn);
      }
      barrier_lds();
    }
  }
}

extern "C" void kernel_launch(void* const* d_in, const int* in_sizes, int n_in,
                              void* d_out, int out_size, void* d_ws, size_t ws_size,
                              hipStream_t stream)
{
  (void)in_sizes; (void)n_in; (void)out_size; (void)ws_size;
  const float* x     = (const float*)d_in[0];
  const unsigned char* xm = (const unsigned char*)d_in[1];
  const float* y     = (const float*)d_in[2];
  const unsigned char* ym = (const unsigned char*)d_in[3];
  const float* Wq_w  = (const float*)d_in[4];
  const float* Wq_b  = (const float*)d_in[5];
  const float* Wup_w = (const float*)d_in[6];
  const float* Wup_b = (const float*)d_in[7];
  const float* Wvp_b = (const float*)d_in[9];
  const float* V_w   = (const float*)d_in[10];
  const float* V_b   = (const float*)d_in[11];
  const float* Wg_w  = (const float*)d_in[12];
  const float* Wg_b  = (const float*)d_in[13];
  const float* W_ih  = (const float*)d_in[14];
  const float* W_hh  = (const float*)d_in[15];
  const float* b_ih  = (const float*)d_in[16];
  const float* b_hh  = (const float*)d_in[17];
  float* out = (float*)d_out;

  float* wsf    = (float*)d_ws;
  float* xp_ws  = wsf;                   // [3072][128]  Ex
  float* yp_ws  = xp_ws + 393216;        // [3072][128]  Ey
  float* ct_ws  = yp_ws + 393216;        // [3072][128]  merged ct
  float* li_ws  = ct_ws + 393216;        // [3072][256]
  float* gx_ws  = li_ws + 786432;        // [3072][512] gate-interleaved
  float* ct2_ws = gx_ws + 1572864;       // [3072][128]  half-1 partial
  float* ml_ws  = ct2_ws + 393216;       // [4][3072]   (m0,l0,m1,l1)

  proj_mfma_kernel<<<dim3(384),256,0,stream>>>(x, y, Wup_w, Wup_b, Wq_w, Wq_b, Wvp_b, xp_ws, yp_ws);
  attn_kernel<<<dim3(48,8,2),256,0,stream>>>(xp_ws, yp_ws, y, xm, ym, V_w, V_b, ct_ws, ct2_ws, ml_ws);
  attn_merge_kernel<<<dim3(384),256,0,stream>>>(ct_ws, ct2_ws, ml_ws, ct_ws);
  mfma_rowgemm_kernel<256><<<dim3(96,4),256,0,stream>>>(x, ct_ws, Wg_w, Wg_b, nullptr, li_ws, 256, 2);
  mfma_rowgemm_kernel<256><<<dim3(96,8),256,0,stream>>>(li_ws, nullptr, W_ih, b_ih, b_hh, gx_ws, 512, 3);
  lstm_kernel<<<dim3(8),512,0,stream>>>(gx_ws, W_hh, out);
}

// Round 11
// 336.597 us; speedup vs baseline: 1.0676x; 1.0045x over previous
//
#include <hip/hip_runtime.h>
#include <hip/hip_bf16.h>
#include <math.h>

typedef __attribute__((ext_vector_type(4))) float  float4v;
typedef __attribute__((ext_vector_type(2))) float  float2v;
typedef __attribute__((ext_vector_type(8))) short  short8;

#define B_ 8
#define L_ 384
#define H_ 128

__device__ __forceinline__ float bflo(unsigned int u){ unsigned int t = u << 16; float f; __builtin_memcpy(&f,&t,4); return f; }
__device__ __forceinline__ unsigned short f2bf(float f){
  unsigned int t; __builtin_memcpy(&t,&f,4);
  return (unsigned short)((t + 0x7fffu + ((t>>16)&1u)) >> 16);
}
__device__ __forceinline__ float fsig(float x){ return __fdividef(1.f, 1.f + __expf(-x)); }

// lgkm-only barrier: LDS ordering without draining in-flight global loads/stores
__device__ __forceinline__ void barrier_lds(){
  asm volatile("s_waitcnt lgkmcnt(0)\n\ts_barrier" ::: "memory");
}

// ---------------- MFMA row-GEMM ----------------
// act==0: linear. act==3: gate-interleaved scatter. act==4: exp2(C2*val).
template<int K>
__device__ __forceinline__ void mfma_rowgemm_body(
    unsigned short* in_s,
    const float* __restrict__ inA,
    const float* __restrict__ W, const float* __restrict__ bias,
    const float* __restrict__ bias2, float* __restrict__ out,
    int Ntotal, int act, int row0, int ob)
{
  constexpr int KP = K + 2;
  const int tid  = threadIdx.x;
  const int w    = tid >> 6;
  const int l    = tid & 63;
  const int c    = l & 15;
  const int quad = l >> 4;

  #pragma unroll
  for (int it = 0; it < K/32; ++it) {
    int idx = it*256 + tid;
    int r = idx / (K/4);
    int k = (idx % (K/4)) * 4;
    float4v f = *(const float4v*)(inA + (size_t)(row0+r)*K + k);
    unsigned int p0 = (unsigned int)f2bf(f.x) | ((unsigned int)f2bf(f.y) << 16);
    unsigned int p1 = (unsigned int)f2bf(f.z) | ((unsigned int)f2bf(f.w) << 16);
    *(unsigned int*)&in_s[r*KP + k]     = p0;
    *(unsigned int*)&in_s[r*KP + k + 2] = p1;
  }

  const int n = ob + w*16 + c;
  short8 bfr[K/32];
  #pragma unroll
  for (int kt = 0; kt < K/32; ++kt) {
    const float* src = W + (size_t)n*K + kt*32 + quad*8;
    float4v f0 = *(const float4v*)(src);
    float4v f1 = *(const float4v*)(src + 4);
    short8 v;
    v[0]=(short)f2bf(f0[0]); v[1]=(short)f2bf(f0[1]); v[2]=(short)f2bf(f0[2]); v[3]=(short)f2bf(f0[3]);
    v[4]=(short)f2bf(f1[0]); v[5]=(short)f2bf(f1[1]); v[6]=(short)f2bf(f1[2]); v[7]=(short)f2bf(f1[3]);
    bfr[kt] = v;
  }
  __syncthreads();

  const float4v z4 = {0.f,0.f,0.f,0.f};
  float4v acc0 = z4, acc1 = z4;
  #pragma unroll
  for (int kt = 0; kt < K/32; ++kt) {
    short8 a0 = *(const short8*)&in_s[(c     )*KP + kt*32 + quad*8];
    short8 a1 = *(const short8*)&in_s[(16 + c)*KP + kt*32 + quad*8];
    acc0 = __builtin_amdgcn_mfma_f32_16x16x32_bf16(a0, bfr[kt], acc0, 0,0,0);
    acc1 = __builtin_amdgcn_mfma_f32_16x16x32_bf16(a1, bfr[kt], acc1, 0,0,0);
  }

  const float C2 = 2.8853900817779268f;   // 2*log2(e)
  float bv = bias[n] + (bias2 ? bias2[n] : 0.f);
  #pragma unroll
  for (int mt = 0; mt < 2; ++mt) {
    float4v A = mt ? acc1 : acc0;
    #pragma unroll
    for (int r = 0; r < 4; ++r) {
      int m = mt*16 + quad*4 + r;
      float val = A[r] + bv;
      if (act == 4)
        val = __builtin_amdgcn_exp2f(C2 * val);
      if (act == 3)
        out[(size_t)(row0+m)*Ntotal + (n & 127)*4 + (n >> 7)] = val;
      else
        out[(size_t)(row0+m)*Ntotal + n] = val;
    }
  }
}

template<int K>
__global__ __launch_bounds__(256) void mfma_rowgemm_kernel(
    const float* __restrict__ inA,
    const float* __restrict__ W, const float* __restrict__ bias,
    const float* __restrict__ bias2, float* __restrict__ out,
    int Ntotal, int act)
{
  __shared__ __align__(16) unsigned short in_s[32*(K+2)];
  mfma_rowgemm_body<K>(in_s, inA, W, bias, bias2, out,
                       Ntotal, act, blockIdx.x*32, blockIdx.y*64);
}

// Projections emit Ex = exp2(C2*x_proj), Ey = exp2(C2*y_proj2)
__global__ __launch_bounds__(256) void proj_mfma_kernel(
    const float* __restrict__ x, const float* __restrict__ y,
    const float* __restrict__ Wup_w, const float* __restrict__ Wup_b,
    const float* __restrict__ Wq_w, const float* __restrict__ Wq_b,
    const float* __restrict__ Wvp_b,
    float* __restrict__ xp, float* __restrict__ yp)
{
  __shared__ __align__(16) unsigned short in_s[32*130];
  int bx = blockIdx.x;
  if (bx < 192)
    mfma_rowgemm_body<128>(in_s, x, Wup_w, Wup_b, nullptr,
                           xp, 128, 4, (bx>>1)*32, (bx&1)*64);
  else {
    bx -= 192;
    mfma_rowgemm_body<128>(in_s, y, Wq_w, Wq_b, Wvp_b,
                           yp, 128, 4, (bx>>1)*32, (bx&1)*64);
  }
}

// Fused additive attention, round-11: 4-way j-split (blockIdx.z in [0,4),
// 96 j each, 3 chunks) -> 1536 blocks (6/CU, 24 waves/CU).
// Pre-exponentiated inputs: term = 1 - 2*rcp(Ex*Ey + 1).
__global__ __launch_bounds__(256) void attn_kernel(
    const float* __restrict__ xp, const float* __restrict__ yp,
    const float* __restrict__ y, const unsigned char* __restrict__ xmask,
    const unsigned char* __restrict__ ymask, const float* __restrict__ Vw,
    const float* __restrict__ Vb,
    float* __restrict__ ctpbase, float* __restrict__ ml)
{
  __shared__ __align__(16) float xp_s[8][128];
  __shared__ __align__(16) float v2_s[128];
  __shared__ __align__(16) float yp_s[32][132];
  __shared__ __align__(16) float yc_s[32][132];
  __shared__ float xm_s[8];
  __shared__ float ym_s[32];
  __shared__ float sv_s;
  const int tid = threadIdx.x;
  const int b   = blockIdx.y;
  const int t0  = blockIdx.x * 8;
  const int jh  = blockIdx.z;      // 4 splits x 96 j
  const int jb  = jh * 96;
  {
    int r = tid >> 5, k4 = (tid & 31) * 4;
    float4v f = *(const float4v*)(xp + ((size_t)(b*L_ + t0 + r))*H_ + k4);
    *(float4v*)&xp_s[r][k4] = f;
    if (tid < 32) {
      float4v v = *(const float4v*)(Vw + tid*4);
      float4v v2; v2[0]=2.f*v[0]; v2[1]=2.f*v[1]; v2[2]=2.f*v[2]; v2[3]=2.f*v[3];
      *(float4v*)&v2_s[tid*4] = v2;
    }
    if (tid < 8) xm_s[tid] = xmask[b*L_ + t0 + tid] ? 0.f : 1.f;
  }
  __syncthreads();
  if (tid < 32) {
    float4v v = *(const float4v*)&v2_s[tid*4];
    float sm = (v[0]+v[1]) + (v[2]+v[3]);
    #pragma unroll
    for (int off = 16; off >= 1; off >>= 1) sm += __shfl_xor(sm, off);
    if (tid == 0) sv_s = 0.5f*sm + Vb[0];
  }

  float4v rp[4], ry[4];
  unsigned char ymb = 0;
  {
    #pragma unroll
    for (int it = 0; it < 4; ++it) {
      int idx = it*256 + tid; int r = idx >> 5; int k4 = (idx & 31) * 4;
      size_t base = ((size_t)(b*L_ + jb + r))*H_ + k4;
      rp[it] = *(const float4v*)(yp + base);
      ry[it] = *(const float4v*)(y + base);
    }
    if (tid < 32) ymb = ymask[b*L_ + jb + tid];
  }

  const int t = tid >> 5, u = tid & 31;
  float mrun = -__builtin_inff(), lrun = 0.f;
  float a0=0.f, a1=0.f, a2=0.f, a3=0.f;
  float svc = 0.f, xmv = 0.f;

  for (int c = 0; c < 3; ++c) {
    __syncthreads();
    #pragma unroll
    for (int it = 0; it < 4; ++it) {
      int idx = it*256 + tid; int r = idx >> 5; int k4 = (idx & 31) * 4;
      *(float4v*)&yp_s[r][k4] = rp[it];
      *(float4v*)&yc_s[r][k4] = ry[it];
    }
    if (tid < 32) ym_s[tid] = ymb ? 0.f : 1.f;
    __syncthreads();
    if (c == 0) { svc = sv_s; xmv = xm_s[t]; }
    if (c < 2) {
      #pragma unroll
      for (int it = 0; it < 4; ++it) {
        int idx = it*256 + tid; int r = idx >> 5; int k4 = (idx & 31) * 4;
        size_t base = ((size_t)(b*L_ + jb + (c+1)*32 + r))*H_ + k4;
        rp[it] = *(const float4v*)(yp + base);
        ry[it] = *(const float4v*)(y + base);
      }
      if (tid < 32) ymb = ymask[b*L_ + jb + (c+1)*32 + tid];
    }

    float sA = 0.f, sB = 0.f;
    {
      const float* yr = yp_s[u];
      const float* xr = xp_s[t];
      #pragma unroll 4
      for (int k = 0; k < 128; k += 4) {
        float4v yv = *(const float4v*)&yr[k];
        float4v xv = *(const float4v*)&xr[k];
        float4v vv = *(const float4v*)&v2_s[k];
        sA -= vv[0] * __builtin_amdgcn_rcpf(__builtin_fmaf(xv[0], yv[0], 1.f));
        sB -= vv[1] * __builtin_amdgcn_rcpf(__builtin_fmaf(xv[1], yv[1], 1.f));
        sA -= vv[2] * __builtin_amdgcn_rcpf(__builtin_fmaf(xv[2], yv[2], 1.f));
        sB -= vv[3] * __builtin_amdgcn_rcpf(__builtin_fmaf(xv[3], yv[3], 1.f));
      }
    }
    float ymv = ym_s[u];
    float s = (svc + sA + sB) * xmv * ymv;
    if (ymv == 0.f) s = -__builtin_inff();
    float mc = s;
    #pragma unroll
    for (int off = 16; off >= 1; off >>= 1) mc = fmaxf(mc, __shfl_xor(mc, off));
    float mnew = fmaxf(mrun, mc);
    float p  = __expf(s - mnew);
    float sc = __expf(mrun - mnew);
    float ps = p;
    #pragma unroll
    for (int off = 16; off >= 1; off >>= 1) ps += __shfl_xor(ps, off);
    lrun = lrun * sc + ps;
    mrun = mnew;
    a0 *= sc; a1 *= sc; a2 *= sc; a3 *= sc;
    #pragma unroll 8
    for (int j = 0; j < 32; ++j) {
      float pv = __shfl(p, j, 32);
      float4v yv = *(const float4v*)&yc_s[j][u*4];
      a0 += pv*yv[0]; a1 += pv*yv[1]; a2 += pv*yv[2]; a3 += pv*yv[3];
    }
  }
  const int row = b*L_ + t0 + t;
  float* ctp = ctpbase + (size_t)jh*393216;
  float4v ov; ov[0]=a0; ov[1]=a1; ov[2]=a2; ov[3]=a3;     // unnormalized
  *(float4v*)(ctp + (size_t)row*H_ + u*4) = ov;
  if (u == 0) {
    ml[(jh*2+0)*3072 + row] = mrun;
    ml[(jh*2+1)*3072 + row] = lrun;
  }
}

// Gating GEMM with INLINE 4-way softmax merge in the staging pass.
// lstm_in = sigmoid(merge@Wg^T + b)*merge, merge=[x | merged-ct].
__global__ __launch_bounds__(256) void gate1_kernel(
    const float* __restrict__ x,
    const float* __restrict__ ctpbase, const float* __restrict__ ml,
    const float* __restrict__ Wg_w, const float* __restrict__ Wg_b,
    float* __restrict__ out)
{
  constexpr int K = 256, KP = 258;
  __shared__ __align__(16) unsigned short in_s[32*KP];
  const int tid  = threadIdx.x;
  const int w    = tid >> 6;
  const int l    = tid & 63;
  const int c    = l & 15;
  const int quad = l >> 4;
  const int row0 = blockIdx.x * 32;
  const int ob   = blockIdx.y * 64;

  #pragma unroll
  for (int it = 0; it < 8; ++it) {
    int idx = it*256 + tid;
    int r = idx >> 6;
    int k = (idx & 63) * 4;
    int row = row0 + r;
    float4v f;
    if (k < 128) {
      f = *(const float4v*)(x + (size_t)row*128 + k);
    } else {
      float m0 = ml[       row], l0 = ml[  3072 + row];
      float m1 = ml[2*3072+row], l1 = ml[3*3072 + row];
      float m2 = ml[4*3072+row], l2 = ml[5*3072 + row];
      float m3 = ml[6*3072+row], l3 = ml[7*3072 + row];
      float mm = fmaxf(fmaxf(m0, m1), fmaxf(m2, m3));
      float e0 = __expf(m0-mm), e1 = __expf(m1-mm);
      float e2 = __expf(m2-mm), e3 = __expf(m3-mm);
      float inv = __fdividef(1.f, (l0*e0 + l1*e1) + (l2*e2 + l3*e3));
      size_t off = (size_t)row*128 + (k-128);
      float4v v0 = *(const float4v*)(ctpbase             + off);
      float4v v1 = *(const float4v*)(ctpbase +   393216  + off);
      float4v v2 = *(const float4v*)(ctpbase + 2*393216  + off);
      float4v v3 = *(const float4v*)(ctpbase + 3*393216  + off);
      f[0] = ((v0[0]*e0 + v1[0]*e1) + (v2[0]*e2 + v3[0]*e3))*inv;
      f[1] = ((v0[1]*e0 + v1[1]*e1) + (v2[1]*e2 + v3[1]*e3))*inv;
      f[2] = ((v0[2]*e0 + v1[2]*e1) + (v2[2]*e2 + v3[2]*e3))*inv;
      f[3] = ((v0[3]*e0 + v1[3]*e1) + (v2[3]*e2 + v3[3]*e3))*inv;
    }
    unsigned int p0 = (unsigned int)f2bf(f[0]) | ((unsigned int)f2bf(f[1]) << 16);
    unsigned int p1 = (unsigned int)f2bf(f[2]) | ((unsigned int)f2bf(f[3]) << 16);
    *(unsigned int*)&in_s[r*KP + k]     = p0;
    *(unsigned int*)&in_s[r*KP + k + 2] = p1;
  }

  const int n = ob + w*16 + c;
  short8 bfr[8];
  #pragma unroll
  for (int kt = 0; kt < 8; ++kt) {
    const float* src = Wg_w + (size_t)n*K + kt*32 + quad*8;
    float4v f0 = *(const float4v*)(src);
    float4v f1 = *(const float4v*)(src + 4);
    short8 v;
    v[0]=(short)f2bf(f0[0]); v[1]=(short)f2bf(f0[1]); v[2]=(short)f2bf(f0[2]); v[3]=(short)f2bf(f0[3]);
    v[4]=(short)f2bf(f1[0]); v[5]=(short)f2bf(f1[1]); v[6]=(short)f2bf(f1[2]); v[7]=(short)f2bf(f1[3]);
    bfr[kt] = v;
  }
  __syncthreads();

  const float4v z4 = {0.f,0.f,0.f,0.f};
  float4v acc0 = z4, acc1 = z4;
  #pragma unroll
  for (int kt = 0; kt < 8; ++kt) {
    short8 a0 = *(const short8*)&in_s[(c     )*KP + kt*32 + quad*8];
    short8 a1 = *(const short8*)&in_s[(16 + c)*KP + kt*32 + quad*8];
    acc0 = __builtin_amdgcn_mfma_f32_16x16x32_bf16(a0, bfr[kt], acc0, 0,0,0);
    acc1 = __builtin_amdgcn_mfma_f32_16x16x32_bf16(a1, bfr[kt], acc1, 0,0,0);
  }

  float bv = Wg_b[n];
  #pragma unroll
  for (int mt = 0; mt < 2; ++mt) {
    float4v A = mt ? acc1 : acc0;
    #pragma unroll
    for (int r = 0; r < 4; ++r) {
      int m = mt*16 + quad*4 + r;
      float val = A[r] + bv;
      float mg = bflo((unsigned int)in_s[m*KP + n]);
      out[(size_t)(row0+m)*256 + n] = fsig(val) * mg;
    }
  }
}

// LSTM scan — round-5 body (measured 180 µs; best). Untouched.
__global__ __launch_bounds__(512) void lstm_kernel(
    const float* __restrict__ gx, const float* __restrict__ Whh,
    float* __restrict__ out)
{
  __shared__ __align__(16) unsigned short h_s[2][128];
  const int tid  = threadIdx.x;
  const int b    = blockIdx.x;
  const int w    = tid >> 6;
  const int l    = tid & 63;
  const int col  = l & 15;
  const int quad = l >> 4;

  short8 bf[4][4];
  #pragma unroll
  for (int nt = 0; nt < 4; ++nt) {
    const int n = nt*128 + w*16 + col;
    #pragma unroll
    for (int kt = 0; kt < 4; ++kt) {
      const int k0 = kt*32 + quad*8;
      const float* src = Whh + (size_t)n*H_ + k0;
      float4v f0 = *(const float4v*)(src);
      float4v f1 = *(const float4v*)(src + 4);
      short8 v;
      v[0]=(short)f2bf(f0[0]); v[1]=(short)f2bf(f0[1]); v[2]=(short)f2bf(f0[2]); v[3]=(short)f2bf(f0[3]);
      v[4]=(short)f2bf(f1[0]); v[5]=(short)f2bf(f1[1]); v[6]=(short)f2bf(f1[2]); v[7]=(short)f2bf(f1[3]);
      bf[nt][kt] = v;
    }
  }

  if (tid < 128) { h_s[0][tid] = 0; h_s[1][tid] = 0; }
  float cst = 0.f;
  const int goff = w*16 + col;
  const float* gbase = gx + (size_t)b*L_*512 + goff*4;
  float* outp = out + (size_t)b*L_*H_ + goff;
  float4v gbuf[4];
  #pragma unroll
  for (int s = 0; s < 4; ++s)
    gbuf[s] = *(const float4v*)(gbase + (size_t)s*512);
  const float4v z4 = {0.f,0.f,0.f,0.f};
  const float NL2E = -1.4426950408889634f;   // -log2(e)
  const float P2L2E = 2.8853900817779268f;   //  2*log2(e)
  __syncthreads();

  for (int t4 = 0; t4 < L_; t4 += 4) {
    #pragma unroll
    for (int s = 0; s < 4; ++s) {
      const int tstep = t4 + s;
      const unsigned short* hb = h_s[s & 1];
      short8 a[4];
      #pragma unroll
      for (int kt=0;kt<4;++kt) a[kt] = *(const short8*)&hb[kt*32 + quad*8];
      float4v c0 = z4, c1 = z4, c2 = z4, c3 = z4;
      #pragma unroll
      for (int kt=0;kt<4;++kt) {
        c0 = __builtin_amdgcn_mfma_f32_16x16x32_bf16(a[kt], bf[0][kt], c0, 0,0,0);
        c1 = __builtin_amdgcn_mfma_f32_16x16x32_bf16(a[kt], bf[1][kt], c1, 0,0,0);
        c2 = __builtin_amdgcn_mfma_f32_16x16x32_bf16(a[kt], bf[2][kt], c2, 0,0,0);
        c3 = __builtin_amdgcn_mfma_f32_16x16x32_bf16(a[kt], bf[3][kt], c3, 0,0,0);
      }
      float g0 = c0[0] + gbuf[s][0];
      float g1 = c1[0] + gbuf[s][1];
      float g2 = c2[0] + gbuf[s][2];
      float g3 = c3[0] + gbuf[s][3];
      if (tstep + 4 < L_)
        gbuf[s] = *(const float4v*)(gbase + (size_t)(tstep+4)*512);
      if (quad == 0) {
        float ig = __builtin_amdgcn_rcpf(1.f + __builtin_amdgcn_exp2f(NL2E*g0));
        float fg = __builtin_amdgcn_rcpf(1.f + __builtin_amdgcn_exp2f(NL2E*g1));
        float gg = 1.f - 2.f*__builtin_amdgcn_rcpf(__builtin_amdgcn_exp2f(P2L2E*g2) + 1.f);
        float og = __builtin_amdgcn_rcpf(1.f + __builtin_amdgcn_exp2f(NL2E*g3));
        cst = fg*cst + ig*gg;
        float hn = og * (1.f - 2.f*__builtin_amdgcn_rcpf(__builtin_amdgcn_exp2f(P2L2E*cst) + 1.f));
        outp[(size_t)tstep*H_] = hn;
        h_s[(s+1)&1][goff] = f2bf(hn);
      }
      barrier_lds();
    }
  }
}

extern "C" void kernel_launch(void* const* d_in, const int* in_sizes, int n_in,
                              void* d_out, int out_size, void* d_ws, size_t ws_size,
                              hipStream_t stream)
{
  (void)in_sizes; (void)n_in; (void)out_size; (void)ws_size;
  const float* x     = (const float*)d_in[0];
  const unsigned char* xm = (const unsigned char*)d_in[1];
  const float* y     = (const float*)d_in[2];
  const unsigned char* ym = (const unsigned char*)d_in[3];
  const float* Wq_w  = (const float*)d_in[4];
  const float* Wq_b  = (const float*)d_in[5];
  const float* Wup_w = (const float*)d_in[6];
  const float* Wup_b = (const float*)d_in[7];
  const float* Wvp_b = (const float*)d_in[9];
  const float* V_w   = (const float*)d_in[10];
  const float* V_b   = (const float*)d_in[11];
  const float* Wg_w  = (const float*)d_in[12];
  const float* Wg_b  = (const float*)d_in[13];
  const float* W_ih  = (const float*)d_in[14];
  const float* W_hh  = (const float*)d_in[15];
  const float* b_ih  = (const float*)d_in[16];
  const float* b_hh  = (const float*)d_in[17];
  float* out = (float*)d_out;

  float* wsf    = (float*)d_ws;
  float* xp_ws  = wsf;                   // [3072][128]  Ex   (li aliases xp+yp)
  float* yp_ws  = xp_ws + 393216;        // [3072][128]  Ey
  float* li_ws  = xp_ws;                 // [3072][256]  (alias: xp/yp dead after attn)
  float* ctp_ws = yp_ws + 393216;        // [4][3072][128] partials
  float* gx_ws  = ctp_ws + 4*393216;     // [3072][512] gate-interleaved
  float* ml_ws  = gx_ws + 1572864;       // [8][3072]   (m_i, l_i)

  proj_mfma_kernel<<<dim3(384),256,0,stream>>>(x, y, Wup_w, Wup_b, Wq_w, Wq_b, Wvp_b, xp_ws, yp_ws);
  attn_kernel<<<dim3(48,8,4),256,0,stream>>>(xp_ws, yp_ws, y, xm, ym, V_w, V_b, ctp_ws, ml_ws);
  gate1_kernel<<<dim3(96,4),256,0,stream>>>(x, ctp_ws, ml_ws, Wg_w, Wg_b, li_ws);
  mfma_rowgemm_kernel<256><<<dim3(96,8),256,0,stream>>>(li_ws, W_ih, b_ih, b_hh, gx_ws, 512, 3);
  lstm_kernel<<<dim3(8),512,0,stream>>>(gx_ws, W_hh, out);
}

// Round 12
// 331.507 us; speedup vs baseline: 1.0840x; 1.0154x over previous
//
#include <hip/hip_runtime.h>
#include <hip/hip_bf16.h>
#include <math.h>

typedef __attribute__((ext_vector_type(4))) float  float4v;
typedef __attribute__((ext_vector_type(2))) float  float2v;
typedef __attribute__((ext_vector_type(8))) short  short8;

#define B_ 8
#define L_ 384
#define H_ 128

__device__ __forceinline__ float bflo(unsigned int u){ unsigned int t = u << 16; float f; __builtin_memcpy(&f,&t,4); return f; }
__device__ __forceinline__ unsigned short f2bf(float f){
  unsigned int t; __builtin_memcpy(&t,&f,4);
  return (unsigned short)((t + 0x7fffu + ((t>>16)&1u)) >> 16);
}
__device__ __forceinline__ float fsig(float x){ return __fdividef(1.f, 1.f + __expf(-x)); }

// lgkm-only barrier: LDS ordering without draining in-flight global loads/stores
__device__ __forceinline__ void barrier_lds(){
  asm volatile("s_waitcnt lgkmcnt(0)\n\ts_barrier" ::: "memory");
}

// ---------------- MFMA row-GEMM ----------------
// act==0: linear. act==3: gate-interleaved scatter. act==4: exp2(C2*val).
template<int K>
__device__ __forceinline__ void mfma_rowgemm_body(
    unsigned short* in_s,
    const float* __restrict__ inA,
    const float* __restrict__ W, const float* __restrict__ bias,
    const float* __restrict__ bias2, float* __restrict__ out,
    int Ntotal, int act, int row0, int ob)
{
  constexpr int KP = K + 2;
  const int tid  = threadIdx.x;
  const int w    = tid >> 6;
  const int l    = tid & 63;
  const int c    = l & 15;
  const int quad = l >> 4;

  #pragma unroll
  for (int it = 0; it < K/32; ++it) {
    int idx = it*256 + tid;
    int r = idx / (K/4);
    int k = (idx % (K/4)) * 4;
    float4v f = *(const float4v*)(inA + (size_t)(row0+r)*K + k);
    unsigned int p0 = (unsigned int)f2bf(f.x) | ((unsigned int)f2bf(f.y) << 16);
    unsigned int p1 = (unsigned int)f2bf(f.z) | ((unsigned int)f2bf(f.w) << 16);
    *(unsigned int*)&in_s[r*KP + k]     = p0;
    *(unsigned int*)&in_s[r*KP + k + 2] = p1;
  }

  const int n = ob + w*16 + c;
  short8 bfr[K/32];
  #pragma unroll
  for (int kt = 0; kt < K/32; ++kt) {
    const float* src = W + (size_t)n*K + kt*32 + quad*8;
    float4v f0 = *(const float4v*)(src);
    float4v f1 = *(const float4v*)(src + 4);
    short8 v;
    v[0]=(short)f2bf(f0[0]); v[1]=(short)f2bf(f0[1]); v[2]=(short)f2bf(f0[2]); v[3]=(short)f2bf(f0[3]);
    v[4]=(short)f2bf(f1[0]); v[5]=(short)f2bf(f1[1]); v[6]=(short)f2bf(f1[2]); v[7]=(short)f2bf(f1[3]);
    bfr[kt] = v;
  }
  __syncthreads();

  const float4v z4 = {0.f,0.f,0.f,0.f};
  float4v acc0 = z4, acc1 = z4;
  #pragma unroll
  for (int kt = 0; kt < K/32; ++kt) {
    short8 a0 = *(const short8*)&in_s[(c     )*KP + kt*32 + quad*8];
    short8 a1 = *(const short8*)&in_s[(16 + c)*KP + kt*32 + quad*8];
    acc0 = __builtin_amdgcn_mfma_f32_16x16x32_bf16(a0, bfr[kt], acc0, 0,0,0);
    acc1 = __builtin_amdgcn_mfma_f32_16x16x32_bf16(a1, bfr[kt], acc1, 0,0,0);
  }

  const float C2 = 2.8853900817779268f;   // 2*log2(e)
  float bv = bias[n] + (bias2 ? bias2[n] : 0.f);
  #pragma unroll
  for (int mt = 0; mt < 2; ++mt) {
    float4v A = mt ? acc1 : acc0;
    #pragma unroll
    for (int r = 0; r < 4; ++r) {
      int m = mt*16 + quad*4 + r;
      float val = A[r] + bv;
      if (act == 4)
        val = __builtin_amdgcn_exp2f(C2 * val);
      if (act == 3)
        out[(size_t)(row0+m)*Ntotal + (n & 127)*4 + (n >> 7)] = val;
      else
        out[(size_t)(row0+m)*Ntotal + n] = val;
    }
  }
}

template<int K>
__global__ __launch_bounds__(256) void mfma_rowgemm_kernel(
    const float* __restrict__ inA,
    const float* __restrict__ W, const float* __restrict__ bias,
    const float* __restrict__ bias2, float* __restrict__ out,
    int Ntotal, int act)
{
  __shared__ __align__(16) unsigned short in_s[32*(K+2)];
  mfma_rowgemm_body<K>(in_s, inA, W, bias, bias2, out,
                       Ntotal, act, blockIdx.x*32, blockIdx.y*64);
}

// Projections emit Ex = exp2(C2*x_proj), Ey = exp2(C2*y_proj2)
__global__ __launch_bounds__(256) void proj_mfma_kernel(
    const float* __restrict__ x, const float* __restrict__ y,
    const float* __restrict__ Wup_w, const float* __restrict__ Wup_b,
    const float* __restrict__ Wq_w, const float* __restrict__ Wq_b,
    const float* __restrict__ Wvp_b,
    float* __restrict__ xp, float* __restrict__ yp)
{
  __shared__ __align__(16) unsigned short in_s[32*130];
  int bx = blockIdx.x;
  if (bx < 192)
    mfma_rowgemm_body<128>(in_s, x, Wup_w, Wup_b, nullptr,
                           xp, 128, 4, (bx>>1)*32, (bx&1)*64);
  else {
    bx -= 192;
    mfma_rowgemm_body<128>(in_s, y, Wq_w, Wq_b, Wvp_b,
                           yp, 128, 4, (bx>>1)*32, (bx&1)*64);
  }
}

// Fused additive attention, round-12: ct accumulation via MFMA.
// Score phase unchanged (pre-exponentiated term = 1 - 2*rcp(Ex*Ey+1)).
// p -> bf16 p_s (A-frag layout), Y loaded as B-frags from global (L2),
// ct kept in MFMA C-registers with online-softmax rescale.
__global__ __launch_bounds__(256) void attn_kernel(
    const float* __restrict__ xp, const float* __restrict__ yp,
    const float* __restrict__ y, const unsigned char* __restrict__ xmask,
    const unsigned char* __restrict__ ymask, const float* __restrict__ Vw,
    const float* __restrict__ Vb,
    float* __restrict__ ctpbase, float* __restrict__ ml)
{
  __shared__ __align__(16) float xp_s[8][128];
  __shared__ __align__(16) float v2_s[128];
  __shared__ __align__(16) float yp_s[32][132];
  __shared__ __align__(16) unsigned short p_s[16][40];   // bf16 A-frag: rows 8-15 unused
  __shared__ float sc_s[16];
  __shared__ float xm_s[8];
  __shared__ float ym_s[32];
  __shared__ float sv_s;
  const int tid = threadIdx.x;
  const int b   = blockIdx.y;
  const int t0  = blockIdx.x * 8;
  const int jh  = blockIdx.z;      // 4 splits x 96 j
  const int jb  = jh * 96;
  const int w    = tid >> 6;       // wave
  const int l    = tid & 63;
  const int c16  = l & 15;
  const int quad = l >> 4;
  {
    int r = tid >> 5, k4 = (tid & 31) * 4;
    float4v f = *(const float4v*)(xp + ((size_t)(b*L_ + t0 + r))*H_ + k4);
    *(float4v*)&xp_s[r][k4] = f;
    if (tid < 32) {
      float4v v = *(const float4v*)(Vw + tid*4);
      float4v v2; v2[0]=2.f*v[0]; v2[1]=2.f*v[1]; v2[2]=2.f*v[2]; v2[3]=2.f*v[3];
      *(float4v*)&v2_s[tid*4] = v2;
    }
    if (tid < 8) xm_s[tid] = xmask[b*L_ + t0 + tid] ? 0.f : 1.f;
    if (tid < 16) sc_s[tid] = 0.f;
    // zero unused p_s rows 8-15 (keeps garbage MFMA rows finite)
    for (int i = 320 + tid; i < 640; i += 256) ((unsigned short*)p_s)[i] = 0;
  }
  __syncthreads();
  if (tid < 32) {
    float4v v = *(const float4v*)&v2_s[tid*4];
    float sm = (v[0]+v[1]) + (v[2]+v[3]);
    #pragma unroll
    for (int off = 16; off >= 1; off >>= 1) sm += __shfl_xor(sm, off);
    if (tid == 0) sv_s = 0.5f*sm + Vb[0];
  }

  float4v rp[4];
  unsigned char ymb = 0;
  {
    #pragma unroll
    for (int it = 0; it < 4; ++it) {
      int idx = it*256 + tid; int r = idx >> 5; int k4 = (idx & 31) * 4;
      rp[it] = *(const float4v*)(yp + ((size_t)(b*L_ + jb + r))*H_ + k4);
    }
    if (tid < 32) ymb = ymask[b*L_ + jb + tid];
  }

  const int t = tid >> 5, u = tid & 31;
  float mrun = -__builtin_inff(), lrun = 0.f;
  const float4v z4 = {0.f,0.f,0.f,0.f};
  float4v acc0 = z4, acc1 = z4;    // ct C-regs: ntiles w and w+4
  float svc = 0.f, xmv = 0.f;

  for (int c = 0; c < 3; ++c) {
    __syncthreads();
    #pragma unroll
    for (int it = 0; it < 4; ++it) {
      int idx = it*256 + tid; int r = idx >> 5; int k4 = (idx & 31) * 4;
      *(float4v*)&yp_s[r][k4] = rp[it];
    }
    if (tid < 32) ym_s[tid] = ymb ? 0.f : 1.f;
    __syncthreads();
    if (c == 0) { svc = sv_s; xmv = xm_s[t]; }
    // y B-frags for this chunk (global/L2; latency hides under score loop):
    // lane (c16,quad) holds Y[k=quad*8+jj][n=nt*16+c16], nt in {w, w+4}
    short8 yb0, yb1;
    {
      const float* ybase = y + ((size_t)(b*L_ + jb + c*32 + quad*8))*H_ + c16;
      #pragma unroll
      for (int jj = 0; jj < 8; ++jj) {
        yb0[jj] = (short)f2bf(ybase[(size_t)jj*H_ + w*16]);
        yb1[jj] = (short)f2bf(ybase[(size_t)jj*H_ + (w+4)*16]);
      }
    }
    if (c < 2) {
      #pragma unroll
      for (int it = 0; it < 4; ++it) {
        int idx = it*256 + tid; int r = idx >> 5; int k4 = (idx & 31) * 4;
        rp[it] = *(const float4v*)(yp + ((size_t)(b*L_ + jb + (c+1)*32 + r))*H_ + k4);
      }
      if (tid < 32) ymb = ymask[b*L_ + jb + (c+1)*32 + tid];
    }

    float sA = 0.f, sB = 0.f;
    {
      const float* yr = yp_s[u];
      const float* xr = xp_s[t];
      #pragma unroll 4
      for (int k = 0; k < 128; k += 4) {
        float4v yv = *(const float4v*)&yr[k];
        float4v xv = *(const float4v*)&xr[k];
        float4v vv = *(const float4v*)&v2_s[k];
        sA -= vv[0] * __builtin_amdgcn_rcpf(__builtin_fmaf(xv[0], yv[0], 1.f));
        sB -= vv[1] * __builtin_amdgcn_rcpf(__builtin_fmaf(xv[1], yv[1], 1.f));
        sA -= vv[2] * __builtin_amdgcn_rcpf(__builtin_fmaf(xv[2], yv[2], 1.f));
        sB -= vv[3] * __builtin_amdgcn_rcpf(__builtin_fmaf(xv[3], yv[3], 1.f));
      }
    }
    float ymv = ym_s[u];
    float s = (svc + sA + sB) * xmv * ymv;
    if (ymv == 0.f) s = -__builtin_inff();
    float mc = s;
    #pragma unroll
    for (int off = 16; off >= 1; off >>= 1) mc = fmaxf(mc, __shfl_xor(mc, off));
    float mnew = fmaxf(mrun, mc);
    float p  = __expf(s - mnew);
    float sc = __expf(mrun - mnew);
    float ps = p;
    #pragma unroll
    for (int off = 16; off >= 1; off >>= 1) ps += __shfl_xor(ps, off);
    lrun = lrun * sc + ps;
    mrun = mnew;
    p_s[t][u] = f2bf(p);
    if (u == 0) sc_s[t] = sc;
    __syncthreads();
    // ct += P @ Y  (one 16x16x32 MFMA per n-tile; rows 8-15 of A are junk
    // but MFMA rows are independent — only rows 0-7 are stored)
    short8 pf = *(const short8*)&p_s[c16][quad*8];
    float4v scv;
    #pragma unroll
    for (int r = 0; r < 4; ++r) scv[r] = sc_s[quad*4 + r];
    acc0 *= scv; acc1 *= scv;
    acc0 = __builtin_amdgcn_mfma_f32_16x16x32_bf16(pf, yb0, acc0, 0,0,0);
    acc1 = __builtin_amdgcn_mfma_f32_16x16x32_bf16(pf, yb1, acc1, 0,0,0);
  }
  // store unnormalized partials: lane holds ct[t=quad*4+r][h=nt*16+c16]
  float* ctp = ctpbase + (size_t)jh*393216;
  if (quad < 2) {
    #pragma unroll
    for (int r = 0; r < 4; ++r) {
      int row = b*L_ + t0 + quad*4 + r;
      ctp[(size_t)row*H_ + w*16 + c16]     = acc0[r];
      ctp[(size_t)row*H_ + (w+4)*16 + c16] = acc1[r];
    }
  }
  if (u == 0) {
    int row = b*L_ + t0 + t;
    ml[(jh*2+0)*3072 + row] = mrun;
    ml[(jh*2+1)*3072 + row] = lrun;
  }
}

// Gating GEMM with INLINE 4-way softmax merge in the staging pass (R11).
__global__ __launch_bounds__(256) void gate1_kernel(
    const float* __restrict__ x,
    const float* __restrict__ ctpbase, const float* __restrict__ ml,
    const float* __restrict__ Wg_w, const float* __restrict__ Wg_b,
    float* __restrict__ out)
{
  constexpr int K = 256, KP = 258;
  __shared__ __align__(16) unsigned short in_s[32*KP];
  const int tid  = threadIdx.x;
  const int w    = tid >> 6;
  const int l    = tid & 63;
  const int c    = l & 15;
  const int quad = l >> 4;
  const int row0 = blockIdx.x * 32;
  const int ob   = blockIdx.y * 64;

  #pragma unroll
  for (int it = 0; it < 8; ++it) {
    int idx = it*256 + tid;
    int r = idx >> 6;
    int k = (idx & 63) * 4;
    int row = row0 + r;
    float4v f;
    if (k < 128) {
      f = *(const float4v*)(x + (size_t)row*128 + k);
    } else {
      float m0 = ml[       row], l0 = ml[  3072 + row];
      float m1 = ml[2*3072+row], l1 = ml[3*3072 + row];
      float m2 = ml[4*3072+row], l2 = ml[5*3072 + row];
      float m3 = ml[6*3072+row], l3 = ml[7*3072 + row];
      float mm = fmaxf(fmaxf(m0, m1), fmaxf(m2, m3));
      float e0 = __expf(m0-mm), e1 = __expf(m1-mm);
      float e2 = __expf(m2-mm), e3 = __expf(m3-mm);
      float inv = __fdividef(1.f, (l0*e0 + l1*e1) + (l2*e2 + l3*e3));
      size_t off = (size_t)row*128 + (k-128);
      float4v v0 = *(const float4v*)(ctpbase             + off);
      float4v v1 = *(const float4v*)(ctpbase +   393216  + off);
      float4v v2 = *(const float4v*)(ctpbase + 2*393216  + off);
      float4v v3 = *(const float4v*)(ctpbase + 3*393216  + off);
      f[0] = ((v0[0]*e0 + v1[0]*e1) + (v2[0]*e2 + v3[0]*e3))*inv;
      f[1] = ((v0[1]*e0 + v1[1]*e1) + (v2[1]*e2 + v3[1]*e3))*inv;
      f[2] = ((v0[2]*e0 + v1[2]*e1) + (v2[2]*e2 + v3[2]*e3))*inv;
      f[3] = ((v0[3]*e0 + v1[3]*e1) + (v2[3]*e2 + v3[3]*e3))*inv;
    }
    unsigned int p0 = (unsigned int)f2bf(f[0]) | ((unsigned int)f2bf(f[1]) << 16);
    unsigned int p1 = (unsigned int)f2bf(f[2]) | ((unsigned int)f2bf(f[3]) << 16);
    *(unsigned int*)&in_s[r*KP + k]     = p0;
    *(unsigned int*)&in_s[r*KP + k + 2] = p1;
  }

  const int n = ob + w*16 + c;
  short8 bfr[8];
  #pragma unroll
  for (int kt = 0; kt < 8; ++kt) {
    const float* src = Wg_w + (size_t)n*K + kt*32 + quad*8;
    float4v f0 = *(const float4v*)(src);
    float4v f1 = *(const float4v*)(src + 4);
    short8 v;
    v[0]=(short)f2bf(f0[0]); v[1]=(short)f2bf(f0[1]); v[2]=(short)f2bf(f0[2]); v[3]=(short)f2bf(f0[3]);
    v[4]=(short)f2bf(f1[0]); v[5]=(short)f2bf(f1[1]); v[6]=(short)f2bf(f1[2]); v[7]=(short)f2bf(f1[3]);
    bfr[kt] = v;
  }
  __syncthreads();

  const float4v z4 = {0.f,0.f,0.f,0.f};
  float4v acc0 = z4, acc1 = z4;
  #pragma unroll
  for (int kt = 0; kt < 8; ++kt) {
    short8 a0 = *(const short8*)&in_s[(c     )*KP + kt*32 + quad*8];
    short8 a1 = *(const short8*)&in_s[(16 + c)*KP + kt*32 + quad*8];
    acc0 = __builtin_amdgcn_mfma_f32_16x16x32_bf16(a0, bfr[kt], acc0, 0,0,0);
    acc1 = __builtin_amdgcn_mfma_f32_16x16x32_bf16(a1, bfr[kt], acc1, 0,0,0);
  }

  float bv = Wg_b[n];
  #pragma unroll
  for (int mt = 0; mt < 2; ++mt) {
    float4v A = mt ? acc1 : acc0;
    #pragma unroll
    for (int r = 0; r < 4; ++r) {
      int m = mt*16 + quad*4 + r;
      float val = A[r] + bv;
      float mg = bflo((unsigned int)in_s[m*KP + n]);
      out[(size_t)(row0+m)*256 + n] = fsig(val) * mg;
    }
  }
}

// LSTM scan — round-5 body (measured 180 µs; best). Untouched.
__global__ __launch_bounds__(512) void lstm_kernel(
    const float* __restrict__ gx, const float* __restrict__ Whh,
    float* __restrict__ out)
{
  __shared__ __align__(16) unsigned short h_s[2][128];
  const int tid  = threadIdx.x;
  const int b    = blockIdx.x;
  const int w    = tid >> 6;
  const int l    = tid & 63;
  const int col  = l & 15;
  const int quad = l >> 4;

  short8 bf[4][4];
  #pragma unroll
  for (int nt = 0; nt < 4; ++nt) {
    const int n = nt*128 + w*16 + col;
    #pragma unroll
    for (int kt = 0; kt < 4; ++kt) {
      const int k0 = kt*32 + quad*8;
      const float* src = Whh + (size_t)n*H_ + k0;
      float4v f0 = *(const float4v*)(src);
      float4v f1 = *(const float4v*)(src + 4);
      short8 v;
      v[0]=(short)f2bf(f0[0]); v[1]=(short)f2bf(f0[1]); v[2]=(short)f2bf(f0[2]); v[3]=(short)f2bf(f0[3]);
      v[4]=(short)f2bf(f1[0]); v[5]=(short)f2bf(f1[1]); v[6]=(short)f2bf(f1[2]); v[7]=(short)f2bf(f1[3]);
      bf[nt][kt] = v;
    }
  }

  if (tid < 128) { h_s[0][tid] = 0; h_s[1][tid] = 0; }
  float cst = 0.f;
  const int goff = w*16 + col;
  const float* gbase = gx + (size_t)b*L_*512 + goff*4;
  float* outp = out + (size_t)b*L_*H_ + goff;
  float4v gbuf[4];
  #pragma unroll
  for (int s = 0; s < 4; ++s)
    gbuf[s] = *(const float4v*)(gbase + (size_t)s*512);
  const float4v z4 = {0.f,0.f,0.f,0.f};
  const float NL2E = -1.4426950408889634f;   // -log2(e)
  const float P2L2E = 2.8853900817779268f;   //  2*log2(e)
  __syncthreads();

  for (int t4 = 0; t4 < L_; t4 += 4) {
    #pragma unroll
    for (int s = 0; s < 4; ++s) {
      const int tstep = t4 + s;
      const unsigned short* hb = h_s[s & 1];
      short8 a[4];
      #pragma unroll
      for (int kt=0;kt<4;++kt) a[kt] = *(const short8*)&hb[kt*32 + quad*8];
      float4v c0 = z4, c1 = z4, c2 = z4, c3 = z4;
      #pragma unroll
      for (int kt=0;kt<4;++kt) {
        c0 = __builtin_amdgcn_mfma_f32_16x16x32_bf16(a[kt], bf[0][kt], c0, 0,0,0);
        c1 = __builtin_amdgcn_mfma_f32_16x16x32_bf16(a[kt], bf[1][kt], c1, 0,0,0);
        c2 = __builtin_amdgcn_mfma_f32_16x16x32_bf16(a[kt], bf[2][kt], c2, 0,0,0);
        c3 = __builtin_amdgcn_mfma_f32_16x16x32_bf16(a[kt], bf[3][kt], c3, 0,0,0);
      }
      float g0 = c0[0] + gbuf[s][0];
      float g1 = c1[0] + gbuf[s][1];
      float g2 = c2[0] + gbuf[s][2];
      float g3 = c3[0] + gbuf[s][3];
      if (tstep + 4 < L_)
        gbuf[s] = *(const float4v*)(gbase + (size_t)(tstep+4)*512);
      if (quad == 0) {
        float ig = __builtin_amdgcn_rcpf(1.f + __builtin_amdgcn_exp2f(NL2E*g0));
        float fg = __builtin_amdgcn_rcpf(1.f + __builtin_amdgcn_exp2f(NL2E*g1));
        float gg = 1.f - 2.f*__builtin_amdgcn_rcpf(__builtin_amdgcn_exp2f(P2L2E*g2) + 1.f);
        float og = __builtin_amdgcn_rcpf(1.f + __builtin_amdgcn_exp2f(NL2E*g3));
        cst = fg*cst + ig*gg;
        float hn = og * (1.f - 2.f*__builtin_amdgcn_rcpf(__builtin_amdgcn_exp2f(P2L2E*cst) + 1.f));
        outp[(size_t)tstep*H_] = hn;
        h_s[(s+1)&1][goff] = f2bf(hn);
      }
      barrier_lds();
    }
  }
}

extern "C" void kernel_launch(void* const* d_in, const int* in_sizes, int n_in,
                              void* d_out, int out_size, void* d_ws, size_t ws_size,
                              hipStream_t stream)
{
  (void)in_sizes; (void)n_in; (void)out_size; (void)ws_size;
  const float* x     = (const float*)d_in[0];
  const unsigned char* xm = (const unsigned char*)d_in[1];
  const float* y     = (const float*)d_in[2];
  const unsigned char* ym = (const unsigned char*)d_in[3];
  const float* Wq_w  = (const float*)d_in[4];
  const float* Wq_b  = (const float*)d_in[5];
  const float* Wup_w = (const float*)d_in[6];
  const float* Wup_b = (const float*)d_in[7];
  const float* Wvp_b = (const float*)d_in[9];
  const float* V_w   = (const float*)d_in[10];
  const float* V_b   = (const float*)d_in[11];
  const float* Wg_w  = (const float*)d_in[12];
  const float* Wg_b  = (const float*)d_in[13];
  const float* W_ih  = (const float*)d_in[14];
  const float* W_hh  = (const float*)d_in[15];
  const float* b_ih  = (const float*)d_in[16];
  const float* b_hh  = (const float*)d_in[17];
  float* out = (float*)d_out;

  float* wsf    = (float*)d_ws;
  float* xp_ws  = wsf;                   // [3072][128]  Ex   (li aliases xp+yp)
  float* yp_ws  = xp_ws + 393216;        // [3072][128]  Ey
  float* li_ws  = xp_ws;                 // [3072][256]  (alias: xp/yp dead after attn)
  float* ctp_ws = yp_ws + 393216;        // [4][3072][128] partials
  float* gx_ws  = ctp_ws + 4*393216;     // [3072][512] gate-interleaved
  float* ml_ws  = gx_ws + 1572864;       // [8][3072]   (m_i, l_i)

  proj_mfma_kernel<<<dim3(384),256,0,stream>>>(x, y, Wup_w, Wup_b, Wq_w, Wq_b, Wvp_b, xp_ws, yp_ws);
  attn_kernel<<<dim3(48,8,4),256,0,stream>>>(xp_ws, yp_ws, y, xm, ym, V_w, V_b, ctp_ws, ml_ws);
  gate1_kernel<<<dim3(96,4),256,0,stream>>>(x, ctp_ws, ml_ws, Wg_w, Wg_b, li_ws);
  mfma_rowgemm_kernel<256><<<dim3(96,8),256,0,stream>>>(li_ws, W_ih, b_ih, b_hh, gx_ws, 512, 3);
  lstm_kernel<<<dim3(8),512,0,stream>>>(gx_ws, W_hh, out);
}

// Round 13
// 330.962 us; speedup vs baseline: 1.0858x; 1.0016x over previous
//
#include <hip/hip_runtime.h>
#include <hip/hip_bf16.h>
#include <math.h>

typedef __attribute__((ext_vector_type(4))) float  float4v;
typedef __attribute__((ext_vector_type(2))) float  float2v;
typedef __attribute__((ext_vector_type(8))) short  short8;

#define B_ 8
#define L_ 384
#define H_ 128

__device__ __forceinline__ float bflo(unsigned int u){ unsigned int t = u << 16; float f; __builtin_memcpy(&f,&t,4); return f; }
__device__ __forceinline__ unsigned short f2bf(float f){
  unsigned int t; __builtin_memcpy(&t,&f,4);
  return (unsigned short)((t + 0x7fffu + ((t>>16)&1u)) >> 16);
}
__device__ __forceinline__ float fsig(float x){ return __fdividef(1.f, 1.f + __expf(-x)); }

// lgkm-only barrier: LDS ordering without draining in-flight global loads/stores
__device__ __forceinline__ void barrier_lds(){
  asm volatile("s_waitcnt lgkmcnt(0)\n\ts_barrier" ::: "memory");
}

// ---------------- MFMA row-GEMM ----------------
// act==0: linear. act==3: gate-interleaved scatter. act==4: exp2(C2*val).
template<int K>
__device__ __forceinline__ void mfma_rowgemm_body(
    unsigned short* in_s,
    const float* __restrict__ inA,
    const float* __restrict__ W, const float* __restrict__ bias,
    const float* __restrict__ bias2, float* __restrict__ out,
    int Ntotal, int act, int row0, int ob)
{
  constexpr int KP = K + 2;
  const int tid  = threadIdx.x;
  const int w    = tid >> 6;
  const int l    = tid & 63;
  const int c    = l & 15;
  const int quad = l >> 4;

  #pragma unroll
  for (int it = 0; it < K/32; ++it) {
    int idx = it*256 + tid;
    int r = idx / (K/4);
    int k = (idx % (K/4)) * 4;
    float4v f = *(const float4v*)(inA + (size_t)(row0+r)*K + k);
    unsigned int p0 = (unsigned int)f2bf(f.x) | ((unsigned int)f2bf(f.y) << 16);
    unsigned int p1 = (unsigned int)f2bf(f.z) | ((unsigned int)f2bf(f.w) << 16);
    *(unsigned int*)&in_s[r*KP + k]     = p0;
    *(unsigned int*)&in_s[r*KP + k + 2] = p1;
  }

  const int n = ob + w*16 + c;
  short8 bfr[K/32];
  #pragma unroll
  for (int kt = 0; kt < K/32; ++kt) {
    const float* src = W + (size_t)n*K + kt*32 + quad*8;
    float4v f0 = *(const float4v*)(src);
    float4v f1 = *(const float4v*)(src + 4);
    short8 v;
    v[0]=(short)f2bf(f0[0]); v[1]=(short)f2bf(f0[1]); v[2]=(short)f2bf(f0[2]); v[3]=(short)f2bf(f0[3]);
    v[4]=(short)f2bf(f1[0]); v[5]=(short)f2bf(f1[1]); v[6]=(short)f2bf(f1[2]); v[7]=(short)f2bf(f1[3]);
    bfr[kt] = v;
  }
  __syncthreads();

  const float4v z4 = {0.f,0.f,0.f,0.f};
  float4v acc0 = z4, acc1 = z4;
  #pragma unroll
  for (int kt = 0; kt < K/32; ++kt) {
    short8 a0 = *(const short8*)&in_s[(c     )*KP + kt*32 + quad*8];
    short8 a1 = *(const short8*)&in_s[(16 + c)*KP + kt*32 + quad*8];
    acc0 = __builtin_amdgcn_mfma_f32_16x16x32_bf16(a0, bfr[kt], acc0, 0,0,0);
    acc1 = __builtin_amdgcn_mfma_f32_16x16x32_bf16(a1, bfr[kt], acc1, 0,0,0);
  }

  const float C2 = 2.8853900817779268f;   // 2*log2(e)
  float bv = bias[n] + (bias2 ? bias2[n] : 0.f);
  #pragma unroll
  for (int mt = 0; mt < 2; ++mt) {
    float4v A = mt ? acc1 : acc0;
    #pragma unroll
    for (int r = 0; r < 4; ++r) {
      int m = mt*16 + quad*4 + r;
      float val = A[r] + bv;
      if (act == 4)
        val = __builtin_amdgcn_exp2f(C2 * val);
      if (act == 3)
        out[(size_t)(row0+m)*Ntotal + (n & 127)*4 + (n >> 7)] = val;
      else
        out[(size_t)(row0+m)*Ntotal + n] = val;
    }
  }
}

template<int K>
__global__ __launch_bounds__(256) void mfma_rowgemm_kernel(
    const float* __restrict__ inA,
    const float* __restrict__ W, const float* __restrict__ bias,
    const float* __restrict__ bias2, float* __restrict__ out,
    int Ntotal, int act)
{
  __shared__ __align__(16) unsigned short in_s[32*(K+2)];
  mfma_rowgemm_body<K>(in_s, inA, W, bias, bias2, out,
                       Ntotal, act, blockIdx.x*32, blockIdx.y*64);
}

// Projections emit Ex = exp2(C2*x_proj), Ey = exp2(C2*y_proj2)
__global__ __launch_bounds__(256) void proj_mfma_kernel(
    const float* __restrict__ x, const float* __restrict__ y,
    const float* __restrict__ Wup_w, const float* __restrict__ Wup_b,
    const float* __restrict__ Wq_w, const float* __restrict__ Wq_b,
    const float* __restrict__ Wvp_b,
    float* __restrict__ xp, float* __restrict__ yp)
{
  __shared__ __align__(16) unsigned short in_s[32*130];
  int bx = blockIdx.x;
  if (bx < 192)
    mfma_rowgemm_body<128>(in_s, x, Wup_w, Wup_b, nullptr,
                           xp, 128, 4, (bx>>1)*32, (bx&1)*64);
  else {
    bx -= 192;
    mfma_rowgemm_body<128>(in_s, y, Wq_w, Wq_b, Wvp_b,
                           yp, 128, 4, (bx>>1)*32, (bx&1)*64);
  }
}

// Fused additive attention (R12): MFMA ct, pre-exponentiated score inputs.
__global__ __launch_bounds__(256) void attn_kernel(
    const float* __restrict__ xp, const float* __restrict__ yp,
    const float* __restrict__ y, const unsigned char* __restrict__ xmask,
    const unsigned char* __restrict__ ymask, const float* __restrict__ Vw,
    const float* __restrict__ Vb,
    float* __restrict__ ctpbase, float* __restrict__ ml)
{
  __shared__ __align__(16) float xp_s[8][128];
  __shared__ __align__(16) float v2_s[128];
  __shared__ __align__(16) float yp_s[32][132];
  __shared__ __align__(16) unsigned short p_s[16][40];   // bf16 A-frag: rows 8-15 unused
  __shared__ float sc_s[16];
  __shared__ float xm_s[8];
  __shared__ float ym_s[32];
  __shared__ float sv_s;
  const int tid = threadIdx.x;
  const int b   = blockIdx.y;
  const int t0  = blockIdx.x * 8;
  const int jh  = blockIdx.z;      // 4 splits x 96 j
  const int jb  = jh * 96;
  const int w    = tid >> 6;       // wave
  const int l    = tid & 63;
  const int c16  = l & 15;
  const int quad = l >> 4;
  {
    int r = tid >> 5, k4 = (tid & 31) * 4;
    float4v f = *(const float4v*)(xp + ((size_t)(b*L_ + t0 + r))*H_ + k4);
    *(float4v*)&xp_s[r][k4] = f;
    if (tid < 32) {
      float4v v = *(const float4v*)(Vw + tid*4);
      float4v v2; v2[0]=2.f*v[0]; v2[1]=2.f*v[1]; v2[2]=2.f*v[2]; v2[3]=2.f*v[3];
      *(float4v*)&v2_s[tid*4] = v2;
    }
    if (tid < 8) xm_s[tid] = xmask[b*L_ + t0 + tid] ? 0.f : 1.f;
    if (tid < 16) sc_s[tid] = 0.f;
    for (int i = 320 + tid; i < 640; i += 256) ((unsigned short*)p_s)[i] = 0;
  }
  __syncthreads();
  if (tid < 32) {
    float4v v = *(const float4v*)&v2_s[tid*4];
    float sm = (v[0]+v[1]) + (v[2]+v[3]);
    #pragma unroll
    for (int off = 16; off >= 1; off >>= 1) sm += __shfl_xor(sm, off);
    if (tid == 0) sv_s = 0.5f*sm + Vb[0];
  }

  float4v rp[4];
  unsigned char ymb = 0;
  {
    #pragma unroll
    for (int it = 0; it < 4; ++it) {
      int idx = it*256 + tid; int r = idx >> 5; int k4 = (idx & 31) * 4;
      rp[it] = *(const float4v*)(yp + ((size_t)(b*L_ + jb + r))*H_ + k4);
    }
    if (tid < 32) ymb = ymask[b*L_ + jb + tid];
  }

  const int t = tid >> 5, u = tid & 31;
  float mrun = -__builtin_inff(), lrun = 0.f;
  const float4v z4 = {0.f,0.f,0.f,0.f};
  float4v acc0 = z4, acc1 = z4;    // ct C-regs: ntiles w and w+4
  float svc = 0.f, xmv = 0.f;

  for (int c = 0; c < 3; ++c) {
    __syncthreads();
    #pragma unroll
    for (int it = 0; it < 4; ++it) {
      int idx = it*256 + tid; int r = idx >> 5; int k4 = (idx & 31) * 4;
      *(float4v*)&yp_s[r][k4] = rp[it];
    }
    if (tid < 32) ym_s[tid] = ymb ? 0.f : 1.f;
    __syncthreads();
    if (c == 0) { svc = sv_s; xmv = xm_s[t]; }
    short8 yb0, yb1;
    {
      const float* ybase = y + ((size_t)(b*L_ + jb + c*32 + quad*8))*H_ + c16;
      #pragma unroll
      for (int jj = 0; jj < 8; ++jj) {
        yb0[jj] = (short)f2bf(ybase[(size_t)jj*H_ + w*16]);
        yb1[jj] = (short)f2bf(ybase[(size_t)jj*H_ + (w+4)*16]);
      }
    }
    if (c < 2) {
      #pragma unroll
      for (int it = 0; it < 4; ++it) {
        int idx = it*256 + tid; int r = idx >> 5; int k4 = (idx & 31) * 4;
        rp[it] = *(const float4v*)(yp + ((size_t)(b*L_ + jb + (c+1)*32 + r))*H_ + k4);
      }
      if (tid < 32) ymb = ymask[b*L_ + jb + (c+1)*32 + tid];
    }

    float sA = 0.f, sB = 0.f;
    {
      const float* yr = yp_s[u];
      const float* xr = xp_s[t];
      #pragma unroll 4
      for (int k = 0; k < 128; k += 4) {
        float4v yv = *(const float4v*)&yr[k];
        float4v xv = *(const float4v*)&xr[k];
        float4v vv = *(const float4v*)&v2_s[k];
        sA -= vv[0] * __builtin_amdgcn_rcpf(__builtin_fmaf(xv[0], yv[0], 1.f));
        sB -= vv[1] * __builtin_amdgcn_rcpf(__builtin_fmaf(xv[1], yv[1], 1.f));
        sA -= vv[2] * __builtin_amdgcn_rcpf(__builtin_fmaf(xv[2], yv[2], 1.f));
        sB -= vv[3] * __builtin_amdgcn_rcpf(__builtin_fmaf(xv[3], yv[3], 1.f));
      }
    }
    float ymv = ym_s[u];
    float s = (svc + sA + sB) * xmv * ymv;
    if (ymv == 0.f) s = -__builtin_inff();
    float mc = s;
    #pragma unroll
    for (int off = 16; off >= 1; off >>= 1) mc = fmaxf(mc, __shfl_xor(mc, off));
    float mnew = fmaxf(mrun, mc);
    float p  = __expf(s - mnew);
    float sc = __expf(mrun - mnew);
    float ps = p;
    #pragma unroll
    for (int off = 16; off >= 1; off >>= 1) ps += __shfl_xor(ps, off);
    lrun = lrun * sc + ps;
    mrun = mnew;
    p_s[t][u] = f2bf(p);
    if (u == 0) sc_s[t] = sc;
    __syncthreads();
    short8 pf = *(const short8*)&p_s[c16][quad*8];
    float4v scv;
    #pragma unroll
    for (int r = 0; r < 4; ++r) scv[r] = sc_s[quad*4 + r];
    acc0 *= scv; acc1 *= scv;
    acc0 = __builtin_amdgcn_mfma_f32_16x16x32_bf16(pf, yb0, acc0, 0,0,0);
    acc1 = __builtin_amdgcn_mfma_f32_16x16x32_bf16(pf, yb1, acc1, 0,0,0);
  }
  float* ctp = ctpbase + (size_t)jh*393216;
  if (quad < 2) {
    #pragma unroll
    for (int r = 0; r < 4; ++r) {
      int row = b*L_ + t0 + quad*4 + r;
      ctp[(size_t)row*H_ + w*16 + c16]     = acc0[r];
      ctp[(size_t)row*H_ + (w+4)*16 + c16] = acc1[r];
    }
  }
  if (u == 0) {
    int row = b*L_ + t0 + t;
    ml[(jh*2+0)*3072 + row] = mrun;
    ml[(jh*2+1)*3072 + row] = lrun;
  }
}

// Gating GEMM with INLINE 4-way softmax merge in the staging pass (R11).
__global__ __launch_bounds__(256) void gate1_kernel(
    const float* __restrict__ x,
    const float* __restrict__ ctpbase, const float* __restrict__ ml,
    const float* __restrict__ Wg_w, const float* __restrict__ Wg_b,
    float* __restrict__ out)
{
  constexpr int K = 256, KP = 258;
  __shared__ __align__(16) unsigned short in_s[32*KP];
  const int tid  = threadIdx.x;
  const int w    = tid >> 6;
  const int l    = tid & 63;
  const int c    = l & 15;
  const int quad = l >> 4;
  const int row0 = blockIdx.x * 32;
  const int ob   = blockIdx.y * 64;

  #pragma unroll
  for (int it = 0; it < 8; ++it) {
    int idx = it*256 + tid;
    int r = idx >> 6;
    int k = (idx & 63) * 4;
    int row = row0 + r;
    float4v f;
    if (k < 128) {
      f = *(const float4v*)(x + (size_t)row*128 + k);
    } else {
      float m0 = ml[       row], l0 = ml[  3072 + row];
      float m1 = ml[2*3072+row], l1 = ml[3*3072 + row];
      float m2 = ml[4*3072+row], l2 = ml[5*3072 + row];
      float m3 = ml[6*3072+row], l3 = ml[7*3072 + row];
      float mm = fmaxf(fmaxf(m0, m1), fmaxf(m2, m3));
      float e0 = __expf(m0-mm), e1 = __expf(m1-mm);
      float e2 = __expf(m2-mm), e3 = __expf(m3-mm);
      float inv = __fdividef(1.f, (l0*e0 + l1*e1) + (l2*e2 + l3*e3));
      size_t off = (size_t)row*128 + (k-128);
      float4v v0 = *(const float4v*)(ctpbase             + off);
      float4v v1 = *(const float4v*)(ctpbase +   393216  + off);
      float4v v2 = *(const float4v*)(ctpbase + 2*393216  + off);
      float4v v3 = *(const float4v*)(ctpbase + 3*393216  + off);
      f[0] = ((v0[0]*e0 + v1[0]*e1) + (v2[0]*e2 + v3[0]*e3))*inv;
      f[1] = ((v0[1]*e0 + v1[1]*e1) + (v2[1]*e2 + v3[1]*e3))*inv;
      f[2] = ((v0[2]*e0 + v1[2]*e1) + (v2[2]*e2 + v3[2]*e3))*inv;
      f[3] = ((v0[3]*e0 + v1[3]*e1) + (v2[3]*e2 + v3[3]*e3))*inv;
    }
    unsigned int p0 = (unsigned int)f2bf(f[0]) | ((unsigned int)f2bf(f[1]) << 16);
    unsigned int p1 = (unsigned int)f2bf(f[2]) | ((unsigned int)f2bf(f[3]) << 16);
    *(unsigned int*)&in_s[r*KP + k]     = p0;
    *(unsigned int*)&in_s[r*KP + k + 2] = p1;
  }

  const int n = ob + w*16 + c;
  short8 bfr[8];
  #pragma unroll
  for (int kt = 0; kt < 8; ++kt) {
    const float* src = Wg_w + (size_t)n*K + kt*32 + quad*8;
    float4v f0 = *(const float4v*)(src);
    float4v f1 = *(const float4v*)(src + 4);
    short8 v;
    v[0]=(short)f2bf(f0[0]); v[1]=(short)f2bf(f0[1]); v[2]=(short)f2bf(f0[2]); v[3]=(short)f2bf(f0[3]);
    v[4]=(short)f2bf(f1[0]); v[5]=(short)f2bf(f1[1]); v[6]=(short)f2bf(f1[2]); v[7]=(short)f2bf(f1[3]);
    bfr[kt] = v;
  }
  __syncthreads();

  const float4v z4 = {0.f,0.f,0.f,0.f};
  float4v acc0 = z4, acc1 = z4;
  #pragma unroll
  for (int kt = 0; kt < 8; ++kt) {
    short8 a0 = *(const short8*)&in_s[(c     )*KP + kt*32 + quad*8];
    short8 a1 = *(const short8*)&in_s[(16 + c)*KP + kt*32 + quad*8];
    acc0 = __builtin_amdgcn_mfma_f32_16x16x32_bf16(a0, bfr[kt], acc0, 0,0,0);
    acc1 = __builtin_amdgcn_mfma_f32_16x16x32_bf16(a1, bfr[kt], acc1, 0,0,0);
  }

  float bv = Wg_b[n];
  #pragma unroll
  for (int mt = 0; mt < 2; ++mt) {
    float4v A = mt ? acc1 : acc0;
    #pragma unroll
    for (int r = 0; r < 4; ++r) {
      int m = mt*16 + quad*4 + r;
      float val = A[r] + bv;
      float mg = bflo((unsigned int)in_s[m*KP + n]);
      out[(size_t)(row0+m)*256 + n] = fsig(val) * mg;
    }
  }
}

// LSTM scan, round-13: MFMA issue reordered so the i/g chains (c0,c2) finish
// in the first half — ig*gg computes UNDER the f/o (c1,c3) MFMA issue window;
// only sig(f), sig(o), cst-fma, tanh(cst) remain after the last MFMA.
// Gate arithmetic unconditional (values replicated across quads; stores
// quad0-masked). Refill hoisted before MFMAs.
__global__ __launch_bounds__(512) void lstm_kernel(
    const float* __restrict__ gx, const float* __restrict__ Whh,
    float* __restrict__ out)
{
  __shared__ __align__(16) unsigned short h_s[2][128];
  const int tid  = threadIdx.x;
  const int b    = blockIdx.x;
  const int w    = tid >> 6;
  const int l    = tid & 63;
  const int col  = l & 15;
  const int quad = l >> 4;

  short8 bf[4][4];
  #pragma unroll
  for (int nt = 0; nt < 4; ++nt) {
    const int n = nt*128 + w*16 + col;
    #pragma unroll
    for (int kt = 0; kt < 4; ++kt) {
      const int k0 = kt*32 + quad*8;
      const float* src = Whh + (size_t)n*H_ + k0;
      float4v f0 = *(const float4v*)(src);
      float4v f1 = *(const float4v*)(src + 4);
      short8 v;
      v[0]=(short)f2bf(f0[0]); v[1]=(short)f2bf(f0[1]); v[2]=(short)f2bf(f0[2]); v[3]=(short)f2bf(f0[3]);
      v[4]=(short)f2bf(f1[0]); v[5]=(short)f2bf(f1[1]); v[6]=(short)f2bf(f1[2]); v[7]=(short)f2bf(f1[3]);
      bf[nt][kt] = v;
    }
  }

  if (tid < 128) { h_s[0][tid] = 0; h_s[1][tid] = 0; }
  float cst = 0.f;
  const int goff = w*16 + col;
  const float* gbase = gx + (size_t)b*L_*512 + goff*4;
  float* outp = out + (size_t)b*L_*H_ + goff;
  float4v gbuf[4];
  #pragma unroll
  for (int s = 0; s < 4; ++s)
    gbuf[s] = *(const float4v*)(gbase + (size_t)s*512);
  const float4v z4 = {0.f,0.f,0.f,0.f};
  const float NL2E = -1.4426950408889634f;   // -log2(e)
  const float P2L2E = 2.8853900817779268f;   //  2*log2(e)
  __syncthreads();

  for (int t4 = 0; t4 < L_; t4 += 4) {
    #pragma unroll
    for (int s = 0; s < 4; ++s) {
      const int tstep = t4 + s;
      const unsigned short* hb = h_s[s & 1];
      short8 a0 = *(const short8*)&hb[ 0 + quad*8];
      short8 a1 = *(const short8*)&hb[32 + quad*8];
      short8 a2 = *(const short8*)&hb[64 + quad*8];
      short8 a3 = *(const short8*)&hb[96 + quad*8];
      float4v gcur = gbuf[s];
      if (tstep + 4 < L_)
        gbuf[s] = *(const float4v*)(gbase + (size_t)(tstep+4)*512);
      // phase 1: chains c2 (g-gate) and c0 (i-gate), kt-interleaved
      float4v c2 = __builtin_amdgcn_mfma_f32_16x16x32_bf16(a0, bf[2][0], z4, 0,0,0);
      float4v c0 = __builtin_amdgcn_mfma_f32_16x16x32_bf16(a0, bf[0][0], z4, 0,0,0);
      c2 = __builtin_amdgcn_mfma_f32_16x16x32_bf16(a1, bf[2][1], c2, 0,0,0);
      c0 = __builtin_amdgcn_mfma_f32_16x16x32_bf16(a1, bf[0][1], c0, 0,0,0);
      c2 = __builtin_amdgcn_mfma_f32_16x16x32_bf16(a2, bf[2][2], c2, 0,0,0);
      c0 = __builtin_amdgcn_mfma_f32_16x16x32_bf16(a2, bf[0][2], c0, 0,0,0);
      c2 = __builtin_amdgcn_mfma_f32_16x16x32_bf16(a3, bf[2][3], c2, 0,0,0);
      c0 = __builtin_amdgcn_mfma_f32_16x16x32_bf16(a3, bf[0][3], c0, 0,0,0);
      // i,g gates + product overlap with phase-2 MFMA issue
      float gg = 1.f - 2.f*__builtin_amdgcn_rcpf(
                   __builtin_amdgcn_exp2f(P2L2E*(c2[0] + gcur[2])) + 1.f);
      float ig = __builtin_amdgcn_rcpf(
                   1.f + __builtin_amdgcn_exp2f(NL2E*(c0[0] + gcur[0])));
      // phase 2: chains c1 (f-gate) and c3 (o-gate)
      float4v c1 = __builtin_amdgcn_mfma_f32_16x16x32_bf16(a0, bf[1][0], z4, 0,0,0);
      float4v c3 = __builtin_amdgcn_mfma_f32_16x16x32_bf16(a0, bf[3][0], z4, 0,0,0);
      float igg = ig * gg;
      c1 = __builtin_amdgcn_mfma_f32_16x16x32_bf16(a1, bf[1][1], c1, 0,0,0);
      c3 = __builtin_amdgcn_mfma_f32_16x16x32_bf16(a1, bf[3][1], c3, 0,0,0);
      c1 = __builtin_amdgcn_mfma_f32_16x16x32_bf16(a2, bf[1][2], c1, 0,0,0);
      c3 = __builtin_amdgcn_mfma_f32_16x16x32_bf16(a2, bf[3][2], c3, 0,0,0);
      c1 = __builtin_amdgcn_mfma_f32_16x16x32_bf16(a3, bf[1][3], c1, 0,0,0);
      c3 = __builtin_amdgcn_mfma_f32_16x16x32_bf16(a3, bf[3][3], c3, 0,0,0);
      float fg = __builtin_amdgcn_rcpf(
                   1.f + __builtin_amdgcn_exp2f(NL2E*(c1[0] + gcur[1])));
      float og = __builtin_amdgcn_rcpf(
                   1.f + __builtin_amdgcn_exp2f(NL2E*(c3[0] + gcur[3])));
      cst = fg*cst + igg;
      float hn = og * (1.f - 2.f*__builtin_amdgcn_rcpf(
                   __builtin_amdgcn_exp2f(P2L2E*cst) + 1.f));
      if (quad == 0) {
        outp[(size_t)tstep*H_] = hn;
        h_s[(s+1)&1][goff] = f2bf(hn);
      }
      barrier_lds();
    }
  }
}

extern "C" void kernel_launch(void* const* d_in, const int* in_sizes, int n_in,
                              void* d_out, int out_size, void* d_ws, size_t ws_size,
                              hipStream_t stream)
{
  (void)in_sizes; (void)n_in; (void)out_size; (void)ws_size;
  const float* x     = (const float*)d_in[0];
  const unsigned char* xm = (const unsigned char*)d_in[1];
  const float* y     = (const float*)d_in[2];
  const unsigned char* ym = (const unsigned char*)d_in[3];
  const float* Wq_w  = (const float*)d_in[4];
  const float* Wq_b  = (const float*)d_in[5];
  const float* Wup_w = (const float*)d_in[6];
  const float* Wup_b = (const float*)d_in[7];
  const float* Wvp_b = (const float*)d_in[9];
  const float* V_w   = (const float*)d_in[10];
  const float* V_b   = (const float*)d_in[11];
  const float* Wg_w  = (const float*)d_in[12];
  const float* Wg_b  = (const float*)d_in[13];
  const float* W_ih  = (const float*)d_in[14];
  const float* W_hh  = (const float*)d_in[15];
  const float* b_ih  = (const float*)d_in[16];
  const float* b_hh  = (const float*)d_in[17];
  float* out = (float*)d_out;

  float* wsf    = (float*)d_ws;
  float* xp_ws  = wsf;                   // [3072][128]  Ex   (li aliases xp+yp)
  float* yp_ws  = xp_ws + 393216;        // [3072][128]  Ey
  float* li_ws  = xp_ws;                 // [3072][256]  (alias: xp/yp dead after attn)
  float* ctp_ws = yp_ws + 393216;        // [4][3072][128] partials
  float* gx_ws  = ctp_ws + 4*393216;     // [3072][512] gate-interleaved
  float* ml_ws  = gx_ws + 1572864;       // [8][3072]   (m_i, l_i)

  proj_mfma_kernel<<<dim3(384),256,0,stream>>>(x, y, Wup_w, Wup_b, Wq_w, Wq_b, Wvp_b, xp_ws, yp_ws);
  attn_kernel<<<dim3(48,8,4),256,0,stream>>>(xp_ws, yp_ws, y, xm, ym, V_w, V_b, ctp_ws, ml_ws);
  gate1_kernel<<<dim3(96,4),256,0,stream>>>(x, ctp_ws, ml_ws, Wg_w, Wg_b, li_ws);
  mfma_rowgemm_kernel<256><<<dim3(96,8),256,0,stream>>>(li_ws, W_ih, b_ih, b_hh, gx_ws, 512, 3);
  lstm_kernel<<<dim3(8),512,0,stream>>>(gx_ws, W_hh, out);
}